// Round 2
// baseline (3110.506 us; speedup 1.0000x reference)
//
#include <hip/hip_runtime.h>

typedef unsigned short u16;
typedef short short8 __attribute__((ext_vector_type(8)));
typedef float floatx4 __attribute__((ext_vector_type(4)));

static constexpr int CB = 16, CT = 256, CMEL = 1024, CD = 512, CH = 8, CDH = 64, CL = 4;
static constexpr int CINTER = 2048, COUT = 80;
static constexpr int CQKV = 3 * CH * CDH;   // 1536

static __device__ __forceinline__ float bf2f(u16 u) {
  union { unsigned u; float f; } v; v.u = ((unsigned)u) << 16; return v.f;
}
static __device__ __forceinline__ u16 f2bf(float f) {  // RNE; inputs finite
  union { float f; unsigned u; } v; v.f = f;
  unsigned r = v.u + 0x7fffu + ((v.u >> 16) & 1u);
  return (u16)(r >> 16);
}

// async global->LDS, 16B per lane; LDS dest = wave-uniform base + lane*16 (m104/m108)
static __device__ __forceinline__ void gld16(const u16* g, u16* lds) {
  __builtin_amdgcn_global_load_lds((const __attribute__((address_space(1))) void*)g,
                                   (__attribute__((address_space(3))) void*)lds, 16, 0, 0);
}

// ===========================================================================
// gemm2_k: 128x128-tile, 4-wave (256 thr) bf16 MFMA GEMM with folded conv taps.
// Kept for the small encoder GEMMs (grid too small for the 256x128 kernel).
// ===========================================================================
template<int NT, bool RELU>
__global__ __launch_bounds__(256)
void gemm2_k(const u16* __restrict__ A, const u16* __restrict__ Bm,
             u16* __restrict__ Cm, const float* __restrict__ bias,
             int M, int N, int K, int lda, int ldb, int ldc,
             int Sm1, long tapStrideB, const u16* __restrict__ zp)
{
  constexpr int BM = 128, BN = 128;
  constexpr int H = (NT == 3) ? 8 : 0;
  constexpr int AR = BM + 2 * H;           // 144 or 128
  __shared__ u16 As[AR * 32];
  __shared__ u16 Bs[NT * BN * 32];

  const int t = threadIdx.x;
  const int lane = t & 63;
  const int wave = t >> 6;                 // 0..3
  const int wrow = wave >> 1;              // 0..1
  const int wcol = wave & 1;               // 0..1
  const int bn0 = blockIdx.x * BN;
  const int bm0 = blockIdx.y * BM;

  floatx4 acc[4][4];
#pragma unroll
  for (int i = 0; i < 4; ++i)
#pragma unroll
    for (int j = 0; j < 4; ++j) acc[i][j] = (floatx4){0.f, 0.f, 0.f, 0.f};

  const int rsub = lane >> 2;
  const int g8 = (((lane & 3) ^ ((lane >> 3) & 3)) << 3);

  // ---- A chunk pointers: chunks {wave, wave+4} (+ chunk 8 by wave 0, NT=3)
  const u16* aP0; const u16* aP1; const u16* aP2 = nullptr;
  {
    int gg0 = bm0 - H + wave * 16 + rsub;
    int gg1 = bm0 - H + (wave + 4) * 16 + rsub;
    aP0 = ((NT == 1) || ((unsigned)gg0 < (unsigned)M)) ? A + (long)gg0 * lda + g8 : nullptr;
    aP1 = ((NT == 1) || ((unsigned)gg1 < (unsigned)M)) ? A + (long)gg1 * lda + g8 : nullptr;
    if (NT == 3 && wave == 0) {
      int gg2 = bm0 - H + 128 + rsub;      // chunk 8
      aP2 = ((unsigned)gg2 < (unsigned)M) ? A + (long)gg2 * lda + g8 : nullptr;
    }
  }
  const int aL0 = wave * 512, aL1 = (wave + 4) * 512, aL2 = 8 * 512;

  // ---- B chunk pointers: per tap, chunks {wave, wave+4}
  const u16* bP[NT][2]; int bL[NT][2];
#pragma unroll
  for (int i = 0; i < NT; ++i)
#pragma unroll
    for (int j = 0; j < 2; ++j) {
      int r = (wave + j * 4) * 16 + rsub;
      bP[i][j] = Bm + (long)i * tapStrideB + (long)(bn0 + r) * ldb + g8;
      bL[i][j] = (i * BN + (wave + j * 4) * 16) * 32;
    }

  const int q = lane >> 4, fm = lane & 15;
  const int swzB = (q ^ ((fm >> 1) & 3)) << 3;
  int swzA[NT];
  bool mv[NT][4];
#pragma unroll
  for (int tap = 0; tap < NT; ++tap) {
    const int dlt = tap - ((NT == 3) ? 1 : 0);
    swzA[tap] = (q ^ ((((H + dlt + fm) & 15) >> 1) & 3)) << 3;
#pragma unroll
    for (int i = 0; i < 4; ++i) {
      int s = (bm0 + wrow * 64 + i * 16 + fm) & Sm1;
      mv[tap][i] = ((unsigned)(s + dlt) <= (unsigned)Sm1);
    }
  }
  const short8 zero8 = {};

  for (int k0 = 0; k0 < K; k0 += 32) {
    gld16(aP0 ? aP0 + k0 : zp, &As[aL0]);
    gld16(aP1 ? aP1 + k0 : zp, &As[aL1]);
    if (NT == 3 && wave == 0) gld16(aP2 ? aP2 + k0 : zp, &As[aL2]);
#pragma unroll
    for (int i = 0; i < NT; ++i)
#pragma unroll
      for (int j = 0; j < 2; ++j) gld16(bP[i][j] + k0, &Bs[bL[i][j]]);
    __syncthreads();

#pragma unroll
    for (int tap = 0; tap < NT; ++tap) {
      const int dlt = tap - ((NT == 3) ? 1 : 0);
      short8 af[4], bfr[4];
#pragma unroll
      for (int i = 0; i < 4; ++i) {
        af[i] = *(const short8*)&As[(wrow * 64 + i * 16 + fm + H + dlt) * 32 + swzA[tap]];
        if (NT == 3 && !mv[tap][i]) af[i] = zero8;
      }
#pragma unroll
      for (int j = 0; j < 4; ++j)
        bfr[j] = *(const short8*)&Bs[(tap * BN + wcol * 64 + j * 16 + fm) * 32 + swzB];
#pragma unroll
      for (int i = 0; i < 4; ++i)
#pragma unroll
        for (int j = 0; j < 4; ++j)
          acc[i][j] = __builtin_amdgcn_mfma_f32_16x16x32_bf16(af[i], bfr[j], acc[i][j], 0, 0, 0);
    }
    __syncthreads();
  }

  const int rbase = bm0 + wrow * 64 + ((lane >> 4) << 2);
  const int cbase = bn0 + wcol * 64 + fm;
#pragma unroll
  for (int j = 0; j < 4; ++j) {
    int col = cbase + j * 16;              // N multiple of 128 for all gemm2 uses
    float bv = bias ? bias[col] : 0.f;
#pragma unroll
    for (int i = 0; i < 4; ++i) {
#pragma unroll
      for (int r = 0; r < 4; ++r) {
        int row = rbase + i * 16 + r;
        float v = acc[i][j][r] + bv;
        if (RELU) v = fmaxf(v, 0.f);
        Cm[(long)row * ldc + col] = f2bf(v);
      }
    }
  }
}

// ===========================================================================
// gemm8_k (R7, resubmitted R8): 256x128-tile, 8-wave (512 thr), explicit
// double-buffered LDS, pipelined schedule per the T3+T4+T5 catalog:
//   - stage(t+1) global_load_lds issued at tile TOP (into the other buffer)
//   - per-tap phases: ds_read -> s_barrier -> lgkmcnt(0)+sched_barrier ->
//     setprio(1) + 16 MFMA + setprio(0) -> s_barrier
//   - single late vmcnt(0) per K-tile (issue-to-wait distance = full tile of
//     compute >> 900-cyc HBM latency; the old structure drained vmcnt(0)
//     right after issuing = the 37% MfmaUtil plateau)
// Staging granules / XOR swizzle / tap-validity masking copied from gemm2_k.
// Requires: M % 256 == 0, N % 128 == 0, K % 64 == 0 (ntiles even).
// ===========================================================================
template<int NT, bool RELU>
__global__ __launch_bounds__(512, 2)
void gemm8_k(const u16* __restrict__ A, const u16* __restrict__ Bm,
             u16* __restrict__ Cm, const float* __restrict__ bias,
             int M, int N, int K, int lda, int ldb, int ldc,
             int Sm1, long tapStrideB, const u16* __restrict__ zp)
{
  constexpr int BM = 256, BN = 128;
  constexpr int H = (NT == 3) ? 8 : 0;
  constexpr int AR = BM + 2 * H;           // 272 or 256
  constexpr int ACH = AR / 16;             // 17 or 16 chunks of 16 rows
  constexpr int BCH = NT * BN / 16;        // 24 or 8
  constexpr int TCH = ACH + BCH;           // 41 or 24
  constexpr int MAXS = (TCH + 7) / 8;      // 6 or 3 staging slots per wave

  __shared__ __attribute__((aligned(16))) u16 As[2][AR * 32];        // 2x17408B / 2x16384B
  __shared__ __attribute__((aligned(16))) u16 Bs[2][NT * BN * 32];   // 2x24576B / 2x8192B

  const int t = threadIdx.x;
  const int lane = t & 63;
  const int w = t >> 6;                    // 0..7
  const int wrow = w >> 1;                 // 0..3  (per-wave 64 rows)
  const int wcol = w & 1;                  // 0..1  (per-wave 64 cols)
  const int bn0 = blockIdx.x * BN;
  const int bm0 = blockIdx.y * BM;

  floatx4 acc[4][4];
#pragma unroll
  for (int i = 0; i < 4; ++i)
#pragma unroll
    for (int j = 0; j < 4; ++j) acc[i][j] = (floatx4){0.f, 0.f, 0.f, 0.f};

  const int rsub = lane >> 2;
  const int g8 = (((lane & 3) ^ ((lane >> 3) & 3)) << 3);

  // ---- staging slot tables: chunk c = w + 8*s; A chunks first, then B (tap-major)
  const u16* sS[MAXS];      // per-lane global src (nullptr -> zp), at k0=0
  int        sOff[MAXS];    // u16 offset within the target buffer
  bool       sIsA[MAXS];
  bool       sUse[MAXS];
#pragma unroll
  for (int s = 0; s < MAXS; ++s) {
    const int c = w + 8 * s;
    sUse[s] = (c < TCH);
    if (c < ACH) {
      sIsA[s] = true;
      sOff[s] = c * 512;                   // 16 rows * 32 cols
      int gg = bm0 - H + c * 16 + rsub;
      sS[s] = ((NT == 1) || ((unsigned)gg < (unsigned)M)) ? A + (long)gg * lda + g8 : nullptr;
    } else {
      sIsA[s] = false;
      const int cb = (c - ACH) < BCH ? (c - ACH) : 0;   // clamp unused slots
      const int tap = cb >> 3, rg = cb & 7;
      sOff[s] = (tap * BN + rg * 16) * 32;
      sS[s] = Bm + (long)tap * tapStrideB + (long)(bn0 + rg * 16 + rsub) * ldb + g8;
    }
  }

  const int q = lane >> 4, fm = lane & 15;
  const int swzB = (q ^ ((fm >> 1) & 3)) << 3;
  int swzA[NT];
  bool mv[NT][4];
#pragma unroll
  for (int tap = 0; tap < NT; ++tap) {
    const int dlt = tap - ((NT == 3) ? 1 : 0);
    swzA[tap] = (q ^ ((((H + dlt + fm) & 15) >> 1) & 3)) << 3;
#pragma unroll
    for (int i = 0; i < 4; ++i) {
      int sq = (bm0 + wrow * 64 + i * 16 + fm) & Sm1;
      mv[tap][i] = ((unsigned)(sq + dlt) <= (unsigned)Sm1);
    }
  }
  const short8 zero8 = {};

  // ---- one K-tile: optionally stage tile(k0+32) into {Awr,Bwr}, compute from {Ard,Brd}
  auto tile = [&](int k0, const u16* Ard, const u16* Brd,
                  u16* Awr, u16* Bwr, bool doStage) {
    if (doStage) {
      const int k1 = k0 + 32;
#pragma unroll
      for (int s = 0; s < MAXS; ++s)
        if (sUse[s]) {
          u16* dst = (sIsA[s] ? Awr : Bwr) + sOff[s];
          gld16(sS[s] ? sS[s] + k1 : zp, dst);
        }
    }
#pragma unroll
    for (int tap = 0; tap < NT; ++tap) {
      const int dlt = tap - ((NT == 3) ? 1 : 0);
      short8 af[4], bfr[4];
#pragma unroll
      for (int i = 0; i < 4; ++i) {
        af[i] = *(const short8*)&Ard[(wrow * 64 + i * 16 + fm + H + dlt) * 32 + swzA[tap]];
        if (NT == 3 && !mv[tap][i]) af[i] = zero8;
      }
#pragma unroll
      for (int j = 0; j < 4; ++j)
        bfr[j] = *(const short8*)&Brd[(tap * BN + wcol * 64 + j * 16 + fm) * 32 + swzB];
      __builtin_amdgcn_s_barrier();
      asm volatile("s_waitcnt lgkmcnt(0)" ::: "memory");
      __builtin_amdgcn_sched_barrier(0);            // rule #18: pin MFMA after the wait
      __builtin_amdgcn_s_setprio(1);
#pragma unroll
      for (int i = 0; i < 4; ++i)
#pragma unroll
        for (int j = 0; j < 4; ++j)
          acc[i][j] = __builtin_amdgcn_mfma_f32_16x16x32_bf16(af[i], bfr[j], acc[i][j], 0, 0, 0);
      __builtin_amdgcn_s_setprio(0);
      if (tap == NT - 1)                            // late wait: stage(t+1) landed
        asm volatile("s_waitcnt vmcnt(0)" ::: "memory");
      __builtin_amdgcn_s_barrier();                 // reads done -> safe to overwrite next
    }
  };

  // ---- prologue: stage tile 0 into buffer 0
#pragma unroll
  for (int s = 0; s < MAXS; ++s)
    if (sUse[s]) {
      u16* dst = (sIsA[s] ? &As[0][0] : &Bs[0][0]) + sOff[s];
      gld16(sS[s] ? sS[s] : zp, dst);
    }
  asm volatile("s_waitcnt vmcnt(0)" ::: "memory");
  __builtin_amdgcn_s_barrier();

  const int ntiles = K >> 5;                        // even for all call sites
  for (int tt = 0; tt < ntiles; tt += 2) {
    tile(tt * 32,      &As[0][0], &Bs[0][0], &As[1][0], &Bs[1][0], tt + 1 < ntiles);
    tile(tt * 32 + 32, &As[1][0], &Bs[1][0], &As[0][0], &Bs[0][0], tt + 2 < ntiles);
  }

  const int rbase = bm0 + wrow * 64 + ((lane >> 4) << 2);
  const int cbase = bn0 + wcol * 64 + fm;
#pragma unroll
  for (int j = 0; j < 4; ++j) {
    int col = cbase + j * 16;              // N multiple of 128 for all gemm8 uses
    float bv = bias ? bias[col] : 0.f;
#pragma unroll
    for (int i = 0; i < 4; ++i) {
#pragma unroll
      for (int r = 0; r < 4; ++r) {
        int row = rbase + i * 16 + r;
        float v = acc[i][j][r] + bv;
        if (RELU) v = fmaxf(v, 0.f);
        Cm[(long)row * ldc + col] = f2bf(v);
      }
    }
  }
}

// ===========================================================================
// attn_k: fused flash attention (unchanged this round).
// ===========================================================================
__global__ __launch_bounds__(512)
void attn_k(const u16* __restrict__ qkv, const u16* __restrict__ vt,
            u16* __restrict__ ctx, const int* __restrict__ lens, int S)
{
  __shared__ __attribute__((aligned(16))) u16 Ks[2][128 * 32];   // [dh-step][kv][32 dh]
  __shared__ __attribute__((aligned(16))) u16 Vts[4][64 * 32];   // [kv-step][dh][32 kv]
  __shared__ __attribute__((aligned(16))) u16 Ps[8][16][136];    // per-wave P [q16][kv128]+pad

  const int t = threadIdx.x, lane = t & 63, w = t >> 6;
  const int bh = blockIdx.y, b = bh >> 3, h = bh & 7;
  const int q0 = blockIdx.x * 128;
  const int len = lens[b];
  const int fm = lane & 15, quad = lane >> 4;
  const int swz8 = ((quad ^ ((fm >> 1) & 3)) << 3);
  const int rsub = lane >> 2;
  const int g8 = (((lane & 3) ^ ((lane >> 3) & 3)) << 3);

  // Q B-frags in registers: B[n=q=fm][k=dh]
  const int qrow = q0 + w * 16 + fm;
  short8 bq[2];
  bq[0] = *(const short8*)&qkv[(long)(b * S + qrow) * CQKV + h * 64 + quad * 8];
  bq[1] = *(const short8*)&qkv[(long)(b * S + qrow) * CQKV + h * 64 + 32 + quad * 8];

  // K staging: 16 chunks (ks in {0,1} x rg in 0..7); wave w takes (w&1, w>>1) and (w&1, w>>1+4)
  const int ksW = w & 1, rgA = w >> 1, rgB = (w >> 1) + 4;
  const u16* kBaseA = qkv + ((long)b * S + rgA * 16 + rsub) * CQKV + CD + h * 64 + ksW * 32 + g8;
  const u16* kBaseB = qkv + ((long)b * S + rgB * 16 + rsub) * CQKV + CD + h * 64 + ksW * 32 + g8;
  u16* kDstA = &Ks[ksW][rgA * 512];
  u16* kDstB = &Ks[ksW][rgB * 512];
  // Vt staging: 16 chunks c = kvs*4 + dhc; wave w takes c = 2w, 2w+1
  const int kvs0 = (2 * w) >> 2, dhc0 = (2 * w) & 3;
  const int kvs1 = (2 * w + 1) >> 2, dhc1 = (2 * w + 1) & 3;
  const u16* vBase0 = vt + ((long)bh * 64 + dhc0 * 16 + rsub) * S + kvs0 * 32 + g8;
  const u16* vBase1 = vt + ((long)bh * 64 + dhc1 * 16 + rsub) * S + kvs1 * 32 + g8;
  u16* vDst0 = &Vts[kvs0][dhc0 * 512];
  u16* vDst1 = &Vts[kvs1][dhc1 * 512];

  floatx4 acc_o[4];
#pragma unroll
  for (int j = 0; j < 4; ++j) acc_o[j] = (floatx4){0.f, 0.f, 0.f, 0.f};
  float m = -1e30f, l = 0.f;

  for (int kv0 = 0; kv0 < S; kv0 += 128) {
    __syncthreads();                      // previous-iter tile reads complete
    gld16(kBaseA + (long)kv0 * CQKV, kDstA);
    gld16(kBaseB + (long)kv0 * CQKV, kDstB);
    gld16(vBase0 + kv0, vDst0);
    gld16(vBase1 + kv0, vDst1);
    __syncthreads();                      // staging visible

    // ---- S^T tile: M=kv 128 (8 frags), N=q 16, K=dh 64 (2 steps)
    floatx4 sa[8];
#pragma unroll
    for (int i = 0; i < 8; ++i) sa[i] = (floatx4){0.f, 0.f, 0.f, 0.f};
#pragma unroll
    for (int ks = 0; ks < 2; ++ks) {
#pragma unroll
      for (int mi = 0; mi < 8; ++mi) {
        short8 ak = *(const short8*)&Ks[ks][(mi * 16 + fm) * 32 + swz8];
        sa[mi] = __builtin_amdgcn_mfma_f32_16x16x32_bf16(ak, bq[ks], sa[mi], 0, 0, 0);
      }
    }

    // ---- online softmax (per q-row = lane&15; kv rows = mi*16 + quad*4 + r)
    float p[8][4], tm = -1e30f;
#pragma unroll
    for (int mi = 0; mi < 8; ++mi)
#pragma unroll
      for (int r = 0; r < 4; ++r) {
        int kvg = kv0 + mi * 16 + quad * 4 + r;
        float v = (kvg <= len) ? sa[mi][r] * 0.125f : -1e30f;
        p[mi][r] = v; tm = fmaxf(tm, v);
      }
    tm = fmaxf(tm, __shfl_xor(tm, 16));
    tm = fmaxf(tm, __shfl_xor(tm, 32));
    const float mnew = fmaxf(m, tm);
    const float al = __expf(m - mnew);
    float ts = 0.f;
#pragma unroll
    for (int mi = 0; mi < 8; ++mi)
#pragma unroll
      for (int r = 0; r < 4; ++r) { float e = __expf(p[mi][r] - mnew); p[mi][r] = e; ts += e; }
    ts += __shfl_xor(ts, 16);
    ts += __shfl_xor(ts, 32);
    l = l * al + ts; m = mnew;
    float al4[4];
#pragma unroll
    for (int r = 0; r < 4; ++r) al4[r] = __shfl(al, ((lane >> 4) << 2) + r, 64);
#pragma unroll
    for (int j = 0; j < 4; ++j)
#pragma unroll
      for (int r = 0; r < 4; ++r) acc_o[j][r] *= al4[r];

    // ---- P -> LDS (wave-private): Ps[w][q=fm][kv = mi*16+quad*4+r]
#pragma unroll
    for (int mi = 0; mi < 8; ++mi) {
      unsigned u01 = (unsigned)f2bf(p[mi][0]) | ((unsigned)f2bf(p[mi][1]) << 16);
      unsigned u23 = (unsigned)f2bf(p[mi][2]) | ((unsigned)f2bf(p[mi][3]) << 16);
      *(uint2*)&Ps[w][fm][mi * 16 + quad * 4] = make_uint2(u01, u23);
    }

    // ---- O += P @ V: M=q 16, N=dh 64 (4 frags), K=kv 128 (4 steps)
#pragma unroll
    for (int kvs = 0; kvs < 4; ++kvs) {
      short8 ap = *(const short8*)&Ps[w][fm][kvs * 32 + quad * 8];
#pragma unroll
      for (int nj = 0; nj < 4; ++nj) {
        short8 bv = *(const short8*)&Vts[kvs][(nj * 16 + fm) * 32 + swz8];
        acc_o[nj] = __builtin_amdgcn_mfma_f32_16x16x32_bf16(ap, bv, acc_o[nj], 0, 0, 0);
      }
    }
  }

  // ---- epilogue: O[q][dh] / l
  float li4[4];
#pragma unroll
  for (int r = 0; r < 4; ++r) li4[r] = 1.f / __shfl(l, ((lane >> 4) << 2) + r, 64);
#pragma unroll
  for (int nj = 0; nj < 4; ++nj)
#pragma unroll
    for (int r = 0; r < 4; ++r) {
      int qr = q0 + w * 16 + quad * 4 + r;
      ctx[(long)(b * S + qr) * CD + h * 64 + nj * 16 + fm] = f2bf(acc_o[nj][r] * li4[r]);
    }
}

// ---------------------------------------------------------------------------
// Final-projection GEMM (N=80), f32 transposed store to d_out.
// ---------------------------------------------------------------------------
template<int BM, int BN>
__global__ __launch_bounds__(256)
void gemmF_k(const u16* __restrict__ A, const u16* __restrict__ Bm,
             float* __restrict__ Cm, const float* __restrict__ bias,
             int M, int N, int K, int lda, int ldb,
             const u16* __restrict__ zp)
{
  __shared__ u16 As[BM * 32];
  __shared__ u16 Bs[BN * 32];

  const int t = threadIdx.x;
  const int lane = t & 63;
  const int wave = t >> 6;
  constexpr int WCOLS = BN / 64;
  const int wrow = wave / WCOLS;
  const int wcol = wave % WCOLS;
  const int bn0 = blockIdx.x * BN;
  const int bm0 = blockIdx.y * BM;

  floatx4 acc[4][4];
#pragma unroll
  for (int i = 0; i < 4; ++i)
#pragma unroll
    for (int j = 0; j < 4; ++j) acc[i][j] = (floatx4){0.f, 0.f, 0.f, 0.f};

  const int rsub = lane >> 2;
  const int g8 = (((lane & 3) ^ ((lane >> 3) & 3)) << 3);
  constexpr int PA = BM / 64, PB = BN / 64;

  const int q = lane >> 4, fm = lane & 15;
  const int swz8 = ((q ^ ((fm >> 1) & 3)) << 3);

  const u16* aP[PA]; const u16* bP[PB];
#pragma unroll
  for (int p = 0; p < PA; ++p)
    aP[p] = A + (long)(bm0 + p * 64 + wave * 16 + rsub) * lda + g8;
#pragma unroll
  for (int p = 0; p < PB; ++p) {
    int r = p * 64 + wave * 16 + rsub;
    bP[p] = ((bn0 + r) < N) ? (Bm + (long)(bn0 + r) * ldb + g8) : nullptr;
  }

  for (int k0 = 0; k0 < K; k0 += 32) {
#pragma unroll
    for (int p = 0; p < PA; ++p)
      gld16(aP[p] + k0, &As[(p * 64 + wave * 16) * 32]);
#pragma unroll
    for (int p = 0; p < PB; ++p)
      gld16(bP[p] ? bP[p] + k0 : zp, &Bs[(p * 64 + wave * 16) * 32]);
    __syncthreads();

    short8 af[4], bfr[4];
#pragma unroll
    for (int i = 0; i < 4; ++i)
      af[i] = *(const short8*)&As[(wrow * 64 + i * 16 + fm) * 32 + swz8];
#pragma unroll
    for (int j = 0; j < 4; ++j)
      bfr[j] = *(const short8*)&Bs[(wcol * 64 + j * 16 + fm) * 32 + swz8];
#pragma unroll
    for (int i = 0; i < 4; ++i)
#pragma unroll
      for (int j = 0; j < 4; ++j)
        acc[i][j] = __builtin_amdgcn_mfma_f32_16x16x32_bf16(af[i], bfr[j], acc[i][j], 0, 0, 0);
    __syncthreads();
  }

  const int rbase = bm0 + wrow * 64 + ((lane >> 4) << 2);
  const int cbase = bn0 + wcol * 64 + (lane & 15);
#pragma unroll
  for (int j = 0; j < 4; ++j) {
    int col = cbase + j * 16;
    if (col >= N) continue;
    float bv = bias ? bias[col] : 0.f;
#pragma unroll
    for (int i = 0; i < 4; ++i) {
#pragma unroll
      for (int r = 0; r < 4; ++r) {
        int row = rbase + i * 16 + r;
        Cm[((long)(row >> 10) * COUT + col) * CMEL + (row & 1023)] = acc[i][j][r] + bv;
      }
    }
  }
}

// ---------------------------------------------------------------------------
// W [tap][K][N] f32 -> WT [tap][N][K] bf16 (LDS-tiled 32x32 transpose)
__global__ void cvt_t_k(const float* __restrict__ src, u16* __restrict__ dst, int K, int N)
{
  const int tap = blockIdx.z;
  const int n0 = blockIdx.x * 32, k0 = blockIdx.y * 32;
  __shared__ float tile[32][33];
  const int t = threadIdx.x;
  const int c = t & 31, rr = t >> 5;
  const float* s = src + (long)tap * K * N;
  u16* d = dst + (long)tap * K * N;
#pragma unroll
  for (int i = 0; i < 4; ++i) {
    int k = k0 + rr + i * 8, n = n0 + c;
    tile[rr + i * 8][c] = (k < K && n < N) ? s[(long)k * N + n] : 0.f;
  }
  __syncthreads();
#pragma unroll
  for (int i = 0; i < 4; ++i) {
    int n = n0 + rr + i * 8, k = k0 + c;
    if (n < N && k < K) d[(long)n * K + k] = f2bf(tile[c][rr + i * 8]);
  }
}

// vt[(b*CH+h)*64 + d][S] = qkv[(b*S+s)*CQKV + 2*CD + h*64 + d]
__global__ void vtr_k(const u16* __restrict__ qkv, u16* __restrict__ vt, int S)
{
  const int s0 = blockIdx.x * 64;
  const int bh = blockIdx.y;
  const int b = bh >> 3, h = bh & 7;
  __shared__ u16 tile[64][65];
  const int t = threadIdx.x;
  const int wave = t >> 6, lane = t & 63;
#pragma unroll
  for (int i = 0; i < 16; ++i) {
    int sl = wave * 16 + i;
    tile[sl][lane] = qkv[(long)(b * S + s0 + sl) * CQKV + 2 * CD + h * 64 + lane];
  }
  __syncthreads();
  const int dl = t >> 2, sc4 = (t & 3) << 4;
  u16* dstp = vt + ((long)bh * 64 + dl) * S + s0 + sc4;
  short8 v0, v1;
#pragma unroll
  for (int j = 0; j < 8; ++j) { v0[j] = (short)tile[sc4 + j][dl]; v1[j] = (short)tile[sc4 + 8 + j][dl]; }
  *(short8*)dstp = v0;
  *(short8*)(dstp + 8) = v1;
}

__global__ void fill_k(float* __restrict__ o, int n, float v)
{
  int i = blockIdx.x * 256 + threadIdx.x;
  if (i < n) o[i] = v;
}

// x[b,t,:] = bf16( 2*emb[tok] + pos[b] )   (reference quirk: pos indexed by BATCH b)
__global__ void embed_k(const int* __restrict__ tok, const float* __restrict__ emb,
                        u16* __restrict__ X)
{
  const long idx = (long)blockIdx.x * 256 + threadIdx.x;
  const int d = (int)(idx & (CD - 1));
  const int m = (int)(idx >> 9);
  const int b = m >> 8;
  const float e = emb[(long)tok[m] * CD + d];
  const int i2 = d >> 1;
  const float den = __expf(-(float)(2 * i2) * (9.210340371976184f / 512.f));
  const float ang = (float)b * den;
  const float p = (d & 1) ? __cosf(ang) : __sinf(ang);
  X[idx] = f2bf(2.f * e + p);
}

// O = LN(X + Y) * g + b ; one block per row, D=512, f32 stats
__global__ void ln_res_k(const u16* __restrict__ X, const u16* __restrict__ Y,
                         const float* __restrict__ g, const float* __restrict__ bta,
                         u16* __restrict__ O)
{
  const int m = blockIdx.x, t = threadIdx.x;
  const long base = (long)m * CD;
  float v0 = bf2f(X[base + t]) + bf2f(Y[base + t]);
  float v1 = bf2f(X[base + t + 256]) + bf2f(Y[base + t + 256]);
  __shared__ float red[256];
  red[t] = v0 + v1; __syncthreads();
  for (int s = 128; s > 0; s >>= 1) { if (t < s) red[t] += red[t + s]; __syncthreads(); }
  const float mean = red[0] * (1.f / 512.f);
  __syncthreads();
  const float d0 = v0 - mean, d1 = v1 - mean;
  red[t] = d0 * d0 + d1 * d1; __syncthreads();
  for (int s = 128; s > 0; s >>= 1) { if (t < s) red[t] += red[t + s]; __syncthreads(); }
  const float rstd = rsqrtf(red[0] * (1.f / 512.f) + 1e-5f);
  O[base + t]       = f2bf(d0 * rstd * g[t] + bta[t]);
  O[base + t + 256] = f2bf(d1 * rstd * g[t + 256] + bta[t + 256]);
}

__global__ void cumsum_k(const int* __restrict__ dur, int* __restrict__ cums)
{
  int b = threadIdx.x;
  if (b < CB) {
    int s = 0;
    for (int t = 0; t < CT; ++t) { s += dur[b * CT + t]; cums[b * CT + t] = s; }
  }
}

__global__ void regulate_k(const u16* __restrict__ xe, const int* __restrict__ cums,
                           const int* __restrict__ mlen, u16* __restrict__ xd)
{
  const int m = blockIdx.x;
  const int b = m >> 10, f = m & (CMEL - 1);
  int lo = 0, hi = CT;
  while (lo < hi) { int mid = (lo + hi) >> 1; if (cums[b * CT + mid] <= f) lo = mid + 1; else hi = mid; }
  const int idx = min(lo, CT - 1);
  const bool keep = (f <= mlen[b]);
  const u16* src = xe + ((long)b * CT + idx) * CD;
  u16* dst = xd + (long)m * CD;
  const int t = threadIdx.x;
  dst[t]       = keep ? src[t] : (u16)0;
  dst[t + 256] = keep ? src[t + 256] : (u16)0;
}

// ---------------------------------------------------------------------------
extern "C" void kernel_launch(void* const* d_in, const int* in_sizes, int n_in,
                              void* d_out, int out_size, void* d_ws, size_t ws_size,
                              hipStream_t stream)
{
  (void)in_sizes; (void)n_in;
  const int*   tokens = (const int*)d_in[0];
  const int*   tlen   = (const int*)d_in[1];
  const int*   mlen   = (const int*)d_in[2];
  const int*   dur    = (const int*)d_in[3];
  const float* emb    = (const float*)d_in[5];
  const float* ew[12]; const float* dw[12];
  for (int i = 0; i < 12; ++i) { ew[i] = (const float*)d_in[6 + i]; dw[i] = (const float*)d_in[18 + i]; }
  const float* out_w = (const float*)d_in[30];
  const float* out_b = (const float*)d_in[31];

  const int Me = CB * CT;       // 4096
  const int Md = CB * CMEL;     // 16384

  const size_t SZ_ZP   = 256;
  const size_t SZ_WBUF = (size_t)3 * CD * CINTER * 2;
  const size_t SZ_XE   = (size_t)Me * CD * 2;
  const size_t SZ_XD   = (size_t)Md * CD * 2;     // x, x1(ctx), yb(vt)
  const size_t SZ_QKV  = (size_t)Md * CQKV * 2;   // 50.3 MB
  const size_t SZ_HB   = (size_t)Md * CINTER * 2; // 67.1 MB
  const size_t SZ_CUMS = (size_t)CB * CT * 4;
  auto al = [](size_t b) { return (b + 255) & ~(size_t)255; };
  size_t U = al(SZ_QKV) > al(SZ_HB) ? al(SZ_QKV) : al(SZ_HB);
  size_t total = al(SZ_ZP) + al(SZ_WBUF) + al(SZ_XE) + 3 * al(SZ_XD) + U + al(SZ_CUMS);
  if (total > ws_size) {
    fill_k<<<dim3((unsigned)((out_size + 255) / 256)), dim3(256), 0, stream>>>(
        (float*)d_out, out_size, 1000.0f);
    return;
  }

  char* p = (char*)d_ws;
  auto take = [&](size_t bytes) { char* r = p; p += al(bytes); return r; };
  u16*  zp   = (u16*)take(SZ_ZP);
  u16*  wbuf = (u16*)take(SZ_WBUF);
  u16*  xe   = (u16*)take(SZ_XE);
  u16*  xd   = (u16*)take(SZ_XD);
  u16*  x1   = (u16*)take(SZ_XD);   // also ctx during attention
  u16*  yb   = (u16*)take(SZ_XD);   // also vt during attention
  char* U0   = take(U);
  u16*  qkvB = (u16*)U0;
  u16*  hb   = (u16*)U0;
  int* cums = (int*)take(SZ_CUMS);

  hipMemsetAsync(zp, 0, SZ_ZP, stream);

  auto cvtT = [&](const float* s, u16* d, int K, int N, int taps) {
    cvt_t_k<<<dim3((unsigned)((N + 31) / 32), (unsigned)((K + 31) / 32), (unsigned)taps),
              dim3(256), 0, stream>>>(s, d, K, N);
  };

  embed_k<<<dim3((unsigned)((long)Me * CD / 256)), dim3(256), 0, stream>>>(tokens, emb, xe);

  auto run_stack = [&](u16* x, int S, int M, const int* lens, const float* const* W) {
    u16* vt = yb;
    const bool big = (M >= 8192);   // decoder: 256x128 pipelined kernel everywhere
    for (int l = 0; l < CL; ++l) {
      // qkv = x @ Wqkv + b
      cvtT(W[0] + (long)l * CD * CQKV, wbuf, CD, CQKV, 1);
      if (big)
        gemm8_k<1, false><<<dim3(CQKV / 128, M / 256), dim3(512), 0, stream>>>(
            x, wbuf, qkvB, W[1] + l * CQKV, M, CQKV, CD, CD, CD, CQKV, S - 1, 0, zp);
      else
        gemm2_k<1, false><<<dim3(CQKV / 128, M / 128), dim3(256), 0, stream>>>(
            x, wbuf, qkvB, W[1] + l * CQKV, M, CQKV, CD, CD, CD, CQKV, S - 1, 0, zp);
      // V^T
      vtr_k<<<dim3((unsigned)(S / 64), (unsigned)(CB * CH)), dim3(256), 0, stream>>>(qkvB, vt, S);
      // fused attention -> ctx (= x1)
      attn_k<<<dim3((unsigned)(S / 128), (unsigned)(CB * CH)), dim3(512), 0, stream>>>(
          qkvB, vt, x1, lens, S);
      // proj: ctx @ Wo + bo -> yb
      cvtT(W[2] + (long)l * CD * CD, wbuf, CD, CD, 1);
      if (big)
        gemm8_k<1, false><<<dim3(CD / 128, M / 256), dim3(512), 0, stream>>>(
            x1, wbuf, yb, W[3] + l * CD, M, CD, CD, CD, CD, CD, S - 1, 0, zp);
      else
        gemm2_k<1, false><<<dim3(CD / 128, M / 128), dim3(256), 0, stream>>>(
            x1, wbuf, yb, W[3] + l * CD, M, CD, CD, CD, CD, CD, S - 1, 0, zp);
      ln_res_k<<<dim3((unsigned)M), dim3(256), 0, stream>>>(x, yb, W[4] + l * CD, W[5] + l * CD, x1);
      // conv1 (3-tap) + relu   (N=2048 -> >=256 blocks even for encoder)
      cvtT(W[6] + (long)l * 3 * CD * CINTER, wbuf, CD, CINTER, 3);
      gemm8_k<3, true><<<dim3(CINTER / 128, M / 256), dim3(512), 0, stream>>>(
          x1, wbuf, hb, W[7] + l * CINTER, M, CINTER, CD, CD, CD, CINTER,
          S - 1, (long)CD * CINTER, zp);
      // conv2 (3-tap)
      cvtT(W[8] + (long)l * 3 * CINTER * CD, wbuf, CINTER, CD, 3);
      if (big)
        gemm8_k<3, false><<<dim3(CD / 128, M / 256), dim3(512), 0, stream>>>(
            hb, wbuf, yb, W[9] + l * CD, M, CD, CINTER, CINTER, CINTER, CD,
            S - 1, (long)CINTER * CD, zp);
      else
        gemm2_k<3, false><<<dim3(CD / 128, M / 128), dim3(256), 0, stream>>>(
            hb, wbuf, yb, W[9] + l * CD, M, CD, CINTER, CINTER, CINTER, CD,
            S - 1, (long)CINTER * CD, zp);
      ln_res_k<<<dim3((unsigned)M), dim3(256), 0, stream>>>(x1, yb, W[10] + l * CD, W[11] + l * CD, x);
    }
  };

  run_stack(xe, CT, Me, tlen, ew);

  cumsum_k<<<dim3(1), dim3(64), 0, stream>>>(dur, cums);
  regulate_k<<<dim3((unsigned)(CB * CMEL)), dim3(256), 0, stream>>>(xe, cums, mlen, xd);

  run_stack(xd, CMEL, Md, mlen, dw);

  // final projection, transposed f32 store straight to d_out
  cvtT(out_w, wbuf, CD, COUT, 1);
  gemmF_k<128, 128><<<dim3(1, Md / 128), dim3(256), 0, stream>>>(
      xd, wbuf, (float*)d_out, out_b, Md, COUT, CD, CD, CD, zp);
}

// Round 6
// 2689.243 us; speedup vs baseline: 1.1566x; 1.1566x over previous
//
#include <hip/hip_runtime.h>

typedef unsigned short u16;
typedef short short8 __attribute__((ext_vector_type(8)));
typedef float floatx4 __attribute__((ext_vector_type(4)));

static constexpr int CB = 16, CT = 256, CMEL = 1024, CD = 512, CH = 8, CDH = 64, CL = 4;
static constexpr int CINTER = 2048, COUT = 80;
static constexpr int CQKV = 3 * CH * CDH;   // 1536

static __device__ __forceinline__ float bf2f(u16 u) {
  union { unsigned u; float f; } v; v.u = ((unsigned)u) << 16; return v.f;
}
static __device__ __forceinline__ u16 f2bf(float f) {  // RNE; inputs finite
  union { float f; unsigned u; } v; v.f = f;
  unsigned r = v.u + 0x7fffu + ((v.u >> 16) & 1u);
  return (u16)(r >> 16);
}

// async global->LDS, 16B per lane; LDS dest = wave-uniform base + lane*16 (m104/m108)
static __device__ __forceinline__ void gld16(const u16* g, u16* lds) {
  __builtin_amdgcn_global_load_lds((const __attribute__((address_space(1))) void*)g,
                                   (__attribute__((address_space(3))) void*)lds, 16, 0, 0);
}

// ===========================================================================
// gemm2_k: 128x128-tile, 4-wave (256 thr) bf16 MFMA GEMM with folded conv taps.
// Proven baseline structure (R0, 2651 us). Used for encoder GEMMs.
// ===========================================================================
template<int NT, bool RELU>
__global__ __launch_bounds__(256)
void gemm2_k(const u16* __restrict__ A, const u16* __restrict__ Bm,
             u16* __restrict__ Cm, const float* __restrict__ bias,
             int M, int N, int K, int lda, int ldb, int ldc,
             int Sm1, long tapStrideB, const u16* __restrict__ zp)
{
  constexpr int BM = 128, BN = 128;
  constexpr int H = (NT == 3) ? 8 : 0;
  constexpr int AR = BM + 2 * H;           // 144 or 128
  __shared__ u16 As[AR * 32];
  __shared__ u16 Bs[NT * BN * 32];

  const int t = threadIdx.x;
  const int lane = t & 63;
  const int wave = t >> 6;                 // 0..3
  const int wrow = wave >> 1;              // 0..1
  const int wcol = wave & 1;               // 0..1
  const int bn0 = blockIdx.x * BN;
  const int bm0 = blockIdx.y * BM;

  floatx4 acc[4][4];
#pragma unroll
  for (int i = 0; i < 4; ++i)
#pragma unroll
    for (int j = 0; j < 4; ++j) acc[i][j] = (floatx4){0.f, 0.f, 0.f, 0.f};

  const int rsub = lane >> 2;
  const int g8 = (((lane & 3) ^ ((lane >> 3) & 3)) << 3);

  // ---- A chunk pointers: chunks {wave, wave+4} (+ chunk 8 by wave 0, NT=3)
  const u16* aP0; const u16* aP1; const u16* aP2 = nullptr;
  {
    int gg0 = bm0 - H + wave * 16 + rsub;
    int gg1 = bm0 - H + (wave + 4) * 16 + rsub;
    aP0 = ((NT == 1) || ((unsigned)gg0 < (unsigned)M)) ? A + (long)gg0 * lda + g8 : nullptr;
    aP1 = ((NT == 1) || ((unsigned)gg1 < (unsigned)M)) ? A + (long)gg1 * lda + g8 : nullptr;
    if (NT == 3 && wave == 0) {
      int gg2 = bm0 - H + 128 + rsub;      // chunk 8
      aP2 = ((unsigned)gg2 < (unsigned)M) ? A + (long)gg2 * lda + g8 : nullptr;
    }
  }
  const int aL0 = wave * 512, aL1 = (wave + 4) * 512, aL2 = 8 * 512;

  // ---- B chunk pointers: per tap, chunks {wave, wave+4}
  const u16* bP[NT][2]; int bL[NT][2];
#pragma unroll
  for (int i = 0; i < NT; ++i)
#pragma unroll
    for (int j = 0; j < 2; ++j) {
      int r = (wave + j * 4) * 16 + rsub;
      bP[i][j] = Bm + (long)i * tapStrideB + (long)(bn0 + r) * ldb + g8;
      bL[i][j] = (i * BN + (wave + j * 4) * 16) * 32;
    }

  const int q = lane >> 4, fm = lane & 15;
  const int swzB = (q ^ ((fm >> 1) & 3)) << 3;
  int swzA[NT];
  bool mv[NT][4];
#pragma unroll
  for (int tap = 0; tap < NT; ++tap) {
    const int dlt = tap - ((NT == 3) ? 1 : 0);
    swzA[tap] = (q ^ ((((H + dlt + fm) & 15) >> 1) & 3)) << 3;
#pragma unroll
    for (int i = 0; i < 4; ++i) {
      int s = (bm0 + wrow * 64 + i * 16 + fm) & Sm1;
      mv[tap][i] = ((unsigned)(s + dlt) <= (unsigned)Sm1);
    }
  }
  const short8 zero8 = {};

  for (int k0 = 0; k0 < K; k0 += 32) {
    gld16(aP0 ? aP0 + k0 : zp, &As[aL0]);
    gld16(aP1 ? aP1 + k0 : zp, &As[aL1]);
    if (NT == 3 && wave == 0) gld16(aP2 ? aP2 + k0 : zp, &As[aL2]);
#pragma unroll
    for (int i = 0; i < NT; ++i)
#pragma unroll
      for (int j = 0; j < 2; ++j) gld16(bP[i][j] + k0, &Bs[bL[i][j]]);
    __syncthreads();

#pragma unroll
    for (int tap = 0; tap < NT; ++tap) {
      const int dlt = tap - ((NT == 3) ? 1 : 0);
      short8 af[4], bfr[4];
#pragma unroll
      for (int i = 0; i < 4; ++i) {
        af[i] = *(const short8*)&As[(wrow * 64 + i * 16 + fm + H + dlt) * 32 + swzA[tap]];
        if (NT == 3 && !mv[tap][i]) af[i] = zero8;
      }
#pragma unroll
      for (int j = 0; j < 4; ++j)
        bfr[j] = *(const short8*)&Bs[(tap * BN + wcol * 64 + j * 16 + fm) * 32 + swzB];
#pragma unroll
      for (int i = 0; i < 4; ++i)
#pragma unroll
        for (int j = 0; j < 4; ++j)
          acc[i][j] = __builtin_amdgcn_mfma_f32_16x16x32_bf16(af[i], bfr[j], acc[i][j], 0, 0, 0);
    }
    __syncthreads();
  }

  const int rbase = bm0 + wrow * 64 + ((lane >> 4) << 2);
  const int cbase = bn0 + wcol * 64 + fm;
#pragma unroll
  for (int j = 0; j < 4; ++j) {
    int col = cbase + j * 16;              // N multiple of 128 for all gemm2 uses
    float bv = bias ? bias[col] : 0.f;
#pragma unroll
    for (int i = 0; i < 4; ++i) {
#pragma unroll
      for (int r = 0; r < 4; ++r) {
        int row = rbase + i * 16 + r;
        float v = acc[i][j][r] + bv;
        if (RELU) v = fmaxf(v, 0.f);
        Cm[(long)row * ldc + col] = f2bf(v);
      }
    }
  }
}

// ===========================================================================
// gemm2p_k: 2-phase double-buffered pipeline expressed with ONLY the
// baseline's primitives. Identical geometry/fragment math to gemm2_k; the one
// structural change is the K-loop order:
//   baseline: stage(cur) -> __syncthreads (zero-distance drain) -> compute
//   here:     stage(next buf) -> compute(cur buf) -> __syncthreads
// __syncthreads' s_waitcnt vmcnt(0)+s_barrier IS the 2-phase per-tile sync:
// by the time it executes, the stage has had a full tile of ds_read+MFMA to
// fly (~900-cyc HBM latency covered), vs the baseline's fully-exposed wait.
// No inline asm, no raw barriers, no setprio (null on lockstep 4-wave, m190).
// LDS: NT=3 67.6 KB -> 2 blocks/CU; NT=1 32.8 KB -> 4 blocks/CU.
// Decoder GEMMs only this round. All call sites: K % 64 == 0.
// ===========================================================================
template<int NT, bool RELU>
__global__ __launch_bounds__(256, 2)
void gemm2p_k(const u16* __restrict__ A, const u16* __restrict__ Bm,
              u16* __restrict__ Cm, const float* __restrict__ bias,
              int M, int N, int K, int lda, int ldb, int ldc,
              int Sm1, long tapStrideB, const u16* __restrict__ zp)
{
  constexpr int BM = 128, BN = 128;
  constexpr int H = (NT == 3) ? 8 : 0;
  constexpr int AR = BM + 2 * H;           // 144 or 128
  __shared__ __attribute__((aligned(16))) u16 As[2][AR * 32];
  __shared__ __attribute__((aligned(16))) u16 Bs[2][NT * BN * 32];

  const int t = threadIdx.x;
  const int lane = t & 63;
  const int wave = t >> 6;                 // 0..3
  const int wrow = wave >> 1;              // 0..1
  const int wcol = wave & 1;               // 0..1
  const int bn0 = blockIdx.x * BN;
  const int bm0 = blockIdx.y * BM;

  floatx4 acc[4][4];
#pragma unroll
  for (int i = 0; i < 4; ++i)
#pragma unroll
    for (int j = 0; j < 4; ++j) acc[i][j] = (floatx4){0.f, 0.f, 0.f, 0.f};

  const int rsub = lane >> 2;
  const int g8 = (((lane & 3) ^ ((lane >> 3) & 3)) << 3);

  // ---- A chunk pointers (identical to gemm2_k)
  const u16* aP0; const u16* aP1; const u16* aP2 = nullptr;
  {
    int gg0 = bm0 - H + wave * 16 + rsub;
    int gg1 = bm0 - H + (wave + 4) * 16 + rsub;
    aP0 = ((NT == 1) || ((unsigned)gg0 < (unsigned)M)) ? A + (long)gg0 * lda + g8 : nullptr;
    aP1 = ((NT == 1) || ((unsigned)gg1 < (unsigned)M)) ? A + (long)gg1 * lda + g8 : nullptr;
    if (NT == 3 && wave == 0) {
      int gg2 = bm0 - H + 128 + rsub;      // chunk 8
      aP2 = ((unsigned)gg2 < (unsigned)M) ? A + (long)gg2 * lda + g8 : nullptr;
    }
  }
  const int aL0 = wave * 512, aL1 = (wave + 4) * 512, aL2 = 8 * 512;

  // ---- B chunk pointers (identical to gemm2_k)
  const u16* bP[NT][2]; int bL[NT][2];
#pragma unroll
  for (int i = 0; i < NT; ++i)
#pragma unroll
    for (int j = 0; j < 2; ++j) {
      int r = (wave + j * 4) * 16 + rsub;
      bP[i][j] = Bm + (long)i * tapStrideB + (long)(bn0 + r) * ldb + g8;
      bL[i][j] = (i * BN + (wave + j * 4) * 16) * 32;
    }

  const int q = lane >> 4, fm = lane & 15;
  const int swzB = (q ^ ((fm >> 1) & 3)) << 3;
  int swzA[NT];
  bool mv[NT][4];
#pragma unroll
  for (int tap = 0; tap < NT; ++tap) {
    const int dlt = tap - ((NT == 3) ? 1 : 0);
    swzA[tap] = (q ^ ((((H + dlt + fm) & 15) >> 1) & 3)) << 3;
#pragma unroll
    for (int i = 0; i < 4; ++i) {
      int s = (bm0 + wrow * 64 + i * 16 + fm) & Sm1;
      mv[tap][i] = ((unsigned)(s + dlt) <= (unsigned)Sm1);
    }
  }
  const short8 zero8 = {};

  // stage one K-tile at k0 into buffer `buf` (identical granules to gemm2_k)
  auto stage = [&](int buf, int k0) {
    gld16(aP0 ? aP0 + k0 : zp, &As[buf][aL0]);
    gld16(aP1 ? aP1 + k0 : zp, &As[buf][aL1]);
    if (NT == 3 && wave == 0) gld16(aP2 ? aP2 + k0 : zp, &As[buf][aL2]);
#pragma unroll
    for (int i = 0; i < NT; ++i)
#pragma unroll
      for (int j = 0; j < 2; ++j) gld16(bP[i][j] + k0, &Bs[buf][bL[i][j]]);
  };

  // compute one K-tile from buffer `rd`; stage k0+32 into `wr` FIRST (2-phase).
  // __syncthreads at the end = vmcnt(0)+lgkmcnt(0)+barrier: stage has landed
  // (RAW for next tile) and all waves' reads of `rd` are done (WAR).
  auto tile = [&](int rd, int wr, int k0) {
    if (k0 + 32 < K) stage(wr, k0 + 32);
#pragma unroll
    for (int tap = 0; tap < NT; ++tap) {
      const int dlt = tap - ((NT == 3) ? 1 : 0);
      short8 af[4], bfr[4];
#pragma unroll
      for (int i = 0; i < 4; ++i) {
        af[i] = *(const short8*)&As[rd][(wrow * 64 + i * 16 + fm + H + dlt) * 32 + swzA[tap]];
        if (NT == 3 && !mv[tap][i]) af[i] = zero8;
      }
#pragma unroll
      for (int j = 0; j < 4; ++j)
        bfr[j] = *(const short8*)&Bs[rd][(tap * BN + wcol * 64 + j * 16 + fm) * 32 + swzB];
#pragma unroll
      for (int i = 0; i < 4; ++i)
#pragma unroll
        for (int j = 0; j < 4; ++j)
          acc[i][j] = __builtin_amdgcn_mfma_f32_16x16x32_bf16(af[i], bfr[j], acc[i][j], 0, 0, 0);
    }
    __syncthreads();
  };

  // prologue: tile 0 into buf 0
  stage(0, 0);
  __syncthreads();

  for (int k0 = 0; k0 < K; k0 += 64) {     // K % 64 == 0 at all call sites
    tile(0, 1, k0);
    tile(1, 0, k0 + 32);
  }

  const int rbase = bm0 + wrow * 64 + ((lane >> 4) << 2);
  const int cbase = bn0 + wcol * 64 + fm;
#pragma unroll
  for (int j = 0; j < 4; ++j) {
    int col = cbase + j * 16;              // N multiple of 128 for all call sites
    float bv = bias ? bias[col] : 0.f;
#pragma unroll
    for (int i = 0; i < 4; ++i) {
#pragma unroll
      for (int r = 0; r < 4; ++r) {
        int row = rbase + i * 16 + r;
        float v = acc[i][j][r] + bv;
        if (RELU) v = fmaxf(v, 0.f);
        Cm[(long)row * ldc + col] = f2bf(v);
      }
    }
  }
}

// ===========================================================================
// attn_k: fused flash attention (unchanged this round).
// ===========================================================================
__global__ __launch_bounds__(512)
void attn_k(const u16* __restrict__ qkv, const u16* __restrict__ vt,
            u16* __restrict__ ctx, const int* __restrict__ lens, int S)
{
  __shared__ __attribute__((aligned(16))) u16 Ks[2][128 * 32];   // [dh-step][kv][32 dh]
  __shared__ __attribute__((aligned(16))) u16 Vts[4][64 * 32];   // [kv-step][dh][32 kv]
  __shared__ __attribute__((aligned(16))) u16 Ps[8][16][136];    // per-wave P [q16][kv128]+pad

  const int t = threadIdx.x, lane = t & 63, w = t >> 6;
  const int bh = blockIdx.y, b = bh >> 3, h = bh & 7;
  const int q0 = blockIdx.x * 128;
  const int len = lens[b];
  const int fm = lane & 15, quad = lane >> 4;
  const int swz8 = ((quad ^ ((fm >> 1) & 3)) << 3);
  const int rsub = lane >> 2;
  const int g8 = (((lane & 3) ^ ((lane >> 3) & 3)) << 3);

  // Q B-frags in registers: B[n=q=fm][k=dh]
  const int qrow = q0 + w * 16 + fm;
  short8 bq[2];
  bq[0] = *(const short8*)&qkv[(long)(b * S + qrow) * CQKV + h * 64 + quad * 8];
  bq[1] = *(const short8*)&qkv[(long)(b * S + qrow) * CQKV + h * 64 + 32 + quad * 8];

  // K staging: 16 chunks (ks in {0,1} x rg in 0..7); wave w takes (w&1, w>>1) and (w&1, w>>1+4)
  const int ksW = w & 1, rgA = w >> 1, rgB = (w >> 1) + 4;
  const u16* kBaseA = qkv + ((long)b * S + rgA * 16 + rsub) * CQKV + CD + h * 64 + ksW * 32 + g8;
  const u16* kBaseB = qkv + ((long)b * S + rgB * 16 + rsub) * CQKV + CD + h * 64 + ksW * 32 + g8;
  u16* kDstA = &Ks[ksW][rgA * 512];
  u16* kDstB = &Ks[ksW][rgB * 512];
  // Vt staging: 16 chunks c = kvs*4 + dhc; wave w takes c = 2w, 2w+1
  const int kvs0 = (2 * w) >> 2, dhc0 = (2 * w) & 3;
  const int kvs1 = (2 * w + 1) >> 2, dhc1 = (2 * w + 1) & 3;
  const u16* vBase0 = vt + ((long)bh * 64 + dhc0 * 16 + rsub) * S + kvs0 * 32 + g8;
  const u16* vBase1 = vt + ((long)bh * 64 + dhc1 * 16 + rsub) * S + kvs1 * 32 + g8;
  u16* vDst0 = &Vts[kvs0][dhc0 * 512];
  u16* vDst1 = &Vts[kvs1][dhc1 * 512];

  floatx4 acc_o[4];
#pragma unroll
  for (int j = 0; j < 4; ++j) acc_o[j] = (floatx4){0.f, 0.f, 0.f, 0.f};
  float m = -1e30f, l = 0.f;

  for (int kv0 = 0; kv0 < S; kv0 += 128) {
    __syncthreads();                      // previous-iter tile reads complete
    gld16(kBaseA + (long)kv0 * CQKV, kDstA);
    gld16(kBaseB + (long)kv0 * CQKV, kDstB);
    gld16(vBase0 + kv0, vDst0);
    gld16(vBase1 + kv0, vDst1);
    __syncthreads();                      // staging visible

    // ---- S^T tile: M=kv 128 (8 frags), N=q 16, K=dh 64 (2 steps)
    floatx4 sa[8];
#pragma unroll
    for (int i = 0; i < 8; ++i) sa[i] = (floatx4){0.f, 0.f, 0.f, 0.f};
#pragma unroll
    for (int ks = 0; ks < 2; ++ks) {
#pragma unroll
      for (int mi = 0; mi < 8; ++mi) {
        short8 ak = *(const short8*)&Ks[ks][(mi * 16 + fm) * 32 + swz8];
        sa[mi] = __builtin_amdgcn_mfma_f32_16x16x32_bf16(ak, bq[ks], sa[mi], 0, 0, 0);
      }
    }

    // ---- online softmax (per q-row = lane&15; kv rows = mi*16 + quad*4 + r)
    float p[8][4], tm = -1e30f;
#pragma unroll
    for (int mi = 0; mi < 8; ++mi)
#pragma unroll
      for (int r = 0; r < 4; ++r) {
        int kvg = kv0 + mi * 16 + quad * 4 + r;
        float v = (kvg <= len) ? sa[mi][r] * 0.125f : -1e30f;
        p[mi][r] = v; tm = fmaxf(tm, v);
      }
    tm = fmaxf(tm, __shfl_xor(tm, 16));
    tm = fmaxf(tm, __shfl_xor(tm, 32));
    const float mnew = fmaxf(m, tm);
    const float al = __expf(m - mnew);
    float ts = 0.f;
#pragma unroll
    for (int mi = 0; mi < 8; ++mi)
#pragma unroll
      for (int r = 0; r < 4; ++r) { float e = __expf(p[mi][r] - mnew); p[mi][r] = e; ts += e; }
    ts += __shfl_xor(ts, 16);
    ts += __shfl_xor(ts, 32);
    l = l * al + ts; m = mnew;
    float al4[4];
#pragma unroll
    for (int r = 0; r < 4; ++r) al4[r] = __shfl(al, ((lane >> 4) << 2) + r, 64);
#pragma unroll
    for (int j = 0; j < 4; ++j)
#pragma unroll
      for (int r = 0; r < 4; ++r) acc_o[j][r] *= al4[r];

    // ---- P -> LDS (wave-private): Ps[w][q=fm][kv = mi*16+quad*4+r]
#pragma unroll
    for (int mi = 0; mi < 8; ++mi) {
      unsigned u01 = (unsigned)f2bf(p[mi][0]) | ((unsigned)f2bf(p[mi][1]) << 16);
      unsigned u23 = (unsigned)f2bf(p[mi][2]) | ((unsigned)f2bf(p[mi][3]) << 16);
      *(uint2*)&Ps[w][fm][mi * 16 + quad * 4] = make_uint2(u01, u23);
    }

    // ---- O += P @ V: M=q 16, N=dh 64 (4 frags), K=kv 128 (4 steps)
#pragma unroll
    for (int kvs = 0; kvs < 4; ++kvs) {
      short8 ap = *(const short8*)&Ps[w][fm][kvs * 32 + quad * 8];
#pragma unroll
      for (int nj = 0; nj < 4; ++nj) {
        short8 bv = *(const short8*)&Vts[kvs][(nj * 16 + fm) * 32 + swz8];
        acc_o[nj] = __builtin_amdgcn_mfma_f32_16x16x32_bf16(ap, bv, acc_o[nj], 0, 0, 0);
      }
    }
  }

  // ---- epilogue: O[q][dh] / l
  float li4[4];
#pragma unroll
  for (int r = 0; r < 4; ++r) li4[r] = 1.f / __shfl(l, ((lane >> 4) << 2) + r, 64);
#pragma unroll
  for (int nj = 0; nj < 4; ++nj)
#pragma unroll
    for (int r = 0; r < 4; ++r) {
      int qr = q0 + w * 16 + quad * 4 + r;
      ctx[(long)(b * S + qr) * CD + h * 64 + nj * 16 + fm] = f2bf(acc_o[nj][r] * li4[r]);
    }
}

// ---------------------------------------------------------------------------
// Final-projection GEMM (N=80), f32 transposed store to d_out.
// ---------------------------------------------------------------------------
template<int BM, int BN>
__global__ __launch_bounds__(256)
void gemmF_k(const u16* __restrict__ A, const u16* __restrict__ Bm,
             float* __restrict__ Cm, const float* __restrict__ bias,
             int M, int N, int K, int lda, int ldb,
             const u16* __restrict__ zp)
{
  __shared__ u16 As[BM * 32];
  __shared__ u16 Bs[BN * 32];

  const int t = threadIdx.x;
  const int lane = t & 63;
  const int wave = t >> 6;
  constexpr int WCOLS = BN / 64;
  const int wrow = wave / WCOLS;
  const int wcol = wave % WCOLS;
  const int bn0 = blockIdx.x * BN;
  const int bm0 = blockIdx.y * BM;

  floatx4 acc[4][4];
#pragma unroll
  for (int i = 0; i < 4; ++i)
#pragma unroll
    for (int j = 0; j < 4; ++j) acc[i][j] = (floatx4){0.f, 0.f, 0.f, 0.f};

  const int rsub = lane >> 2;
  const int g8 = (((lane & 3) ^ ((lane >> 3) & 3)) << 3);
  constexpr int PA = BM / 64, PB = BN / 64;

  const int q = lane >> 4, fm = lane & 15;
  const int swz8 = ((q ^ ((fm >> 1) & 3)) << 3);

  const u16* aP[PA]; const u16* bP[PB];
#pragma unroll
  for (int p = 0; p < PA; ++p)
    aP[p] = A + (long)(bm0 + p * 64 + wave * 16 + rsub) * lda + g8;
#pragma unroll
  for (int p = 0; p < PB; ++p) {
    int r = p * 64 + wave * 16 + rsub;
    bP[p] = ((bn0 + r) < N) ? (Bm + (long)(bn0 + r) * ldb + g8) : nullptr;
  }

  for (int k0 = 0; k0 < K; k0 += 32) {
#pragma unroll
    for (int p = 0; p < PA; ++p)
      gld16(aP[p] + k0, &As[(p * 64 + wave * 16) * 32]);
#pragma unroll
    for (int p = 0; p < PB; ++p)
      gld16(bP[p] ? bP[p] + k0 : zp, &Bs[(p * 64 + wave * 16) * 32]);
    __syncthreads();

    short8 af[4], bfr[4];
#pragma unroll
    for (int i = 0; i < 4; ++i)
      af[i] = *(const short8*)&As[(wrow * 64 + i * 16 + fm) * 32 + swz8];
#pragma unroll
    for (int j = 0; j < 4; ++j)
      bfr[j] = *(const short8*)&Bs[(wcol * 64 + j * 16 + fm) * 32 + swz8];
#pragma unroll
    for (int i = 0; i < 4; ++i)
#pragma unroll
      for (int j = 0; j < 4; ++j)
        acc[i][j] = __builtin_amdgcn_mfma_f32_16x16x32_bf16(af[i], bfr[j], acc[i][j], 0, 0, 0);
    __syncthreads();
  }

  const int rbase = bm0 + wrow * 64 + ((lane >> 4) << 2);
  const int cbase = bn0 + wcol * 64 + (lane & 15);
#pragma unroll
  for (int j = 0; j < 4; ++j) {
    int col = cbase + j * 16;
    if (col >= N) continue;
    float bv = bias ? bias[col] : 0.f;
#pragma unroll
    for (int i = 0; i < 4; ++i) {
#pragma unroll
      for (int r = 0; r < 4; ++r) {
        int row = rbase + i * 16 + r;
        Cm[((long)(row >> 10) * COUT + col) * CMEL + (row & 1023)] = acc[i][j][r] + bv;
      }
    }
  }
}

// ---------------------------------------------------------------------------
// W [tap][K][N] f32 -> WT [tap][N][K] bf16 (LDS-tiled 32x32 transpose)
__global__ void cvt_t_k(const float* __restrict__ src, u16* __restrict__ dst, int K, int N)
{
  const int tap = blockIdx.z;
  const int n0 = blockIdx.x * 32, k0 = blockIdx.y * 32;
  __shared__ float tile[32][33];
  const int t = threadIdx.x;
  const int c = t & 31, rr = t >> 5;
  const float* s = src + (long)tap * K * N;
  u16* d = dst + (long)tap * K * N;
#pragma unroll
  for (int i = 0; i < 4; ++i) {
    int k = k0 + rr + i * 8, n = n0 + c;
    tile[rr + i * 8][c] = (k < K && n < N) ? s[(long)k * N + n] : 0.f;
  }
  __syncthreads();
#pragma unroll
  for (int i = 0; i < 4; ++i) {
    int n = n0 + rr + i * 8, k = k0 + c;
    if (n < N && k < K) d[(long)n * K + k] = f2bf(tile[c][rr + i * 8]);
  }
}

// vt[(b*CH+h)*64 + d][S] = qkv[(b*S+s)*CQKV + 2*CD + h*64 + d]
__global__ void vtr_k(const u16* __restrict__ qkv, u16* __restrict__ vt, int S)
{
  const int s0 = blockIdx.x * 64;
  const int bh = blockIdx.y;
  const int b = bh >> 3, h = bh & 7;
  __shared__ u16 tile[64][65];
  const int t = threadIdx.x;
  const int wave = t >> 6, lane = t & 63;
#pragma unroll
  for (int i = 0; i < 16; ++i) {
    int sl = wave * 16 + i;
    tile[sl][lane] = qkv[(long)(b * S + s0 + sl) * CQKV + 2 * CD + h * 64 + lane];
  }
  __syncthreads();
  const int dl = t >> 2, sc4 = (t & 3) << 4;
  u16* dstp = vt + ((long)bh * 64 + dl) * S + s0 + sc4;
  short8 v0, v1;
#pragma unroll
  for (int j = 0; j < 8; ++j) { v0[j] = (short)tile[sc4 + j][dl]; v1[j] = (short)tile[sc4 + 8 + j][dl]; }
  *(short8*)dstp = v0;
  *(short8*)(dstp + 8) = v1;
}

__global__ void fill_k(float* __restrict__ o, int n, float v)
{
  int i = blockIdx.x * 256 + threadIdx.x;
  if (i < n) o[i] = v;
}

// x[b,t,:] = bf16( 2*emb[tok] + pos[b] )   (reference quirk: pos indexed by BATCH b)
__global__ void embed_k(const int* __restrict__ tok, const float* __restrict__ emb,
                        u16* __restrict__ X)
{
  const long idx = (long)blockIdx.x * 256 + threadIdx.x;
  const int d = (int)(idx & (CD - 1));
  const int m = (int)(idx >> 9);
  const int b = m >> 8;
  const float e = emb[(long)tok[m] * CD + d];
  const int i2 = d >> 1;
  const float den = __expf(-(float)(2 * i2) * (9.210340371976184f / 512.f));
  const float ang = (float)b * den;
  const float p = (d & 1) ? __cosf(ang) : __sinf(ang);
  X[idx] = f2bf(2.f * e + p);
}

// O = LN(X + Y) * g + b ; one block per row, D=512, f32 stats
__global__ void ln_res_k(const u16* __restrict__ X, const u16* __restrict__ Y,
                         const float* __restrict__ g, const float* __restrict__ bta,
                         u16* __restrict__ O)
{
  const int m = blockIdx.x, t = threadIdx.x;
  const long base = (long)m * CD;
  float v0 = bf2f(X[base + t]) + bf2f(Y[base + t]);
  float v1 = bf2f(X[base + t + 256]) + bf2f(Y[base + t + 256]);
  __shared__ float red[256];
  red[t] = v0 + v1; __syncthreads();
  for (int s = 128; s > 0; s >>= 1) { if (t < s) red[t] += red[t + s]; __syncthreads(); }
  const float mean = red[0] * (1.f / 512.f);
  __syncthreads();
  const float d0 = v0 - mean, d1 = v1 - mean;
  red[t] = d0 * d0 + d1 * d1; __syncthreads();
  for (int s = 128; s > 0; s >>= 1) { if (t < s) red[t] += red[t + s]; __syncthreads(); }
  const float rstd = rsqrtf(red[0] * (1.f / 512.f) + 1e-5f);
  O[base + t]       = f2bf(d0 * rstd * g[t] + bta[t]);
  O[base + t + 256] = f2bf(d1 * rstd * g[t + 256] + bta[t + 256]);
}

__global__ void cumsum_k(const int* __restrict__ dur, int* __restrict__ cums)
{
  int b = threadIdx.x;
  if (b < CB) {
    int s = 0;
    for (int t = 0; t < CT; ++t) { s += dur[b * CT + t]; cums[b * CT + t] = s; }
  }
}

__global__ void regulate_k(const u16* __restrict__ xe, const int* __restrict__ cums,
                           const int* __restrict__ mlen, u16* __restrict__ xd)
{
  const int m = blockIdx.x;
  const int b = m >> 10, f = m & (CMEL - 1);
  int lo = 0, hi = CT;
  while (lo < hi) { int mid = (lo + hi) >> 1; if (cums[b * CT + mid] <= f) lo = mid + 1; else hi = mid; }
  const int idx = min(lo, CT - 1);
  const bool keep = (f <= mlen[b]);
  const u16* src = xe + ((long)b * CT + idx) * CD;
  u16* dst = xd + (long)m * CD;
  const int t = threadIdx.x;
  dst[t]       = keep ? src[t] : (u16)0;
  dst[t + 256] = keep ? src[t + 256] : (u16)0;
}

// ---------------------------------------------------------------------------
extern "C" void kernel_launch(void* const* d_in, const int* in_sizes, int n_in,
                              void* d_out, int out_size, void* d_ws, size_t ws_size,
                              hipStream_t stream)
{
  (void)in_sizes; (void)n_in;
  const int*   tokens = (const int*)d_in[0];
  const int*   tlen   = (const int*)d_in[1];
  const int*   mlen   = (const int*)d_in[2];
  const int*   dur    = (const int*)d_in[3];
  const float* emb    = (const float*)d_in[5];
  const float* ew[12]; const float* dw[12];
  for (int i = 0; i < 12; ++i) { ew[i] = (const float*)d_in[6 + i]; dw[i] = (const float*)d_in[18 + i]; }
  const float* out_w = (const float*)d_in[30];
  const float* out_b = (const float*)d_in[31];

  const int Me = CB * CT;       // 4096
  const int Md = CB * CMEL;     // 16384

  const size_t SZ_ZP   = 256;
  const size_t SZ_WBUF = (size_t)3 * CD * CINTER * 2;
  const size_t SZ_XE   = (size_t)Me * CD * 2;
  const size_t SZ_XD   = (size_t)Md * CD * 2;     // x, x1(ctx), yb(vt)
  const size_t SZ_QKV  = (size_t)Md * CQKV * 2;   // 50.3 MB
  const size_t SZ_HB   = (size_t)Md * CINTER * 2; // 67.1 MB
  const size_t SZ_CUMS = (size_t)CB * CT * 4;
  auto al = [](size_t b) { return (b + 255) & ~(size_t)255; };
  size_t U = al(SZ_QKV) > al(SZ_HB) ? al(SZ_QKV) : al(SZ_HB);
  size_t total = al(SZ_ZP) + al(SZ_WBUF) + al(SZ_XE) + 3 * al(SZ_XD) + U + al(SZ_CUMS);
  if (total > ws_size) {
    fill_k<<<dim3((unsigned)((out_size + 255) / 256)), dim3(256), 0, stream>>>(
        (float*)d_out, out_size, 1000.0f);
    return;
  }

  char* p = (char*)d_ws;
  auto take = [&](size_t bytes) { char* r = p; p += al(bytes); return r; };
  u16*  zp   = (u16*)take(SZ_ZP);
  u16*  wbuf = (u16*)take(SZ_WBUF);
  u16*  xe   = (u16*)take(SZ_XE);
  u16*  xd   = (u16*)take(SZ_XD);
  u16*  x1   = (u16*)take(SZ_XD);   // also ctx during attention
  u16*  yb   = (u16*)take(SZ_XD);   // also vt during attention
  char* U0   = take(U);
  u16*  qkvB = (u16*)U0;
  u16*  hb   = (u16*)U0;
  int* cums = (int*)take(SZ_CUMS);

  hipMemsetAsync(zp, 0, SZ_ZP, stream);

  auto cvtT = [&](const float* s, u16* d, int K, int N, int taps) {
    cvt_t_k<<<dim3((unsigned)((N + 31) / 32), (unsigned)((K + 31) / 32), (unsigned)taps),
              dim3(256), 0, stream>>>(s, d, K, N);
  };

  embed_k<<<dim3((unsigned)((long)Me * CD / 256)), dim3(256), 0, stream>>>(tokens, emb, xe);

  auto run_stack = [&](u16* x, int S, int M, const int* lens, const float* const* W) {
    u16* vt = yb;
    const bool big = (M >= 8192);   // decoder: 2-phase pipelined kernel
    for (int l = 0; l < CL; ++l) {
      // qkv = x @ Wqkv + b
      cvtT(W[0] + (long)l * CD * CQKV, wbuf, CD, CQKV, 1);
      if (big)
        gemm2p_k<1, false><<<dim3(CQKV / 128, M / 128), dim3(256), 0, stream>>>(
            x, wbuf, qkvB, W[1] + l * CQKV, M, CQKV, CD, CD, CD, CQKV, S - 1, 0, zp);
      else
        gemm2_k<1, false><<<dim3(CQKV / 128, M / 128), dim3(256), 0, stream>>>(
            x, wbuf, qkvB, W[1] + l * CQKV, M, CQKV, CD, CD, CD, CQKV, S - 1, 0, zp);
      // V^T
      vtr_k<<<dim3((unsigned)(S / 64), (unsigned)(CB * CH)), dim3(256), 0, stream>>>(qkvB, vt, S);
      // fused attention -> ctx (= x1)
      attn_k<<<dim3((unsigned)(S / 128), (unsigned)(CB * CH)), dim3(512), 0, stream>>>(
          qkvB, vt, x1, lens, S);
      // proj: ctx @ Wo + bo -> yb
      cvtT(W[2] + (long)l * CD * CD, wbuf, CD, CD, 1);
      if (big)
        gemm2p_k<1, false><<<dim3(CD / 128, M / 128), dim3(256), 0, stream>>>(
            x1, wbuf, yb, W[3] + l * CD, M, CD, CD, CD, CD, CD, S - 1, 0, zp);
      else
        gemm2_k<1, false><<<dim3(CD / 128, M / 128), dim3(256), 0, stream>>>(
            x1, wbuf, yb, W[3] + l * CD, M, CD, CD, CD, CD, CD, S - 1, 0, zp);
      ln_res_k<<<dim3((unsigned)M), dim3(256), 0, stream>>>(x, yb, W[4] + l * CD, W[5] + l * CD, x1);
      // conv1 (3-tap) + relu
      cvtT(W[6] + (long)l * 3 * CD * CINTER, wbuf, CD, CINTER, 3);
      if (big)
        gemm2p_k<3, true><<<dim3(CINTER / 128, M / 128), dim3(256), 0, stream>>>(
            x1, wbuf, hb, W[7] + l * CINTER, M, CINTER, CD, CD, CD, CINTER,
            S - 1, (long)CD * CINTER, zp);
      else
        gemm2_k<3, true><<<dim3(CINTER / 128, M / 128), dim3(256), 0, stream>>>(
            x1, wbuf, hb, W[7] + l * CINTER, M, CINTER, CD, CD, CD, CINTER,
            S - 1, (long)CD * CINTER, zp);
      // conv2 (3-tap)
      cvtT(W[8] + (long)l * 3 * CINTER * CD, wbuf, CINTER, CD, 3);
      if (big)
        gemm2p_k<3, false><<<dim3(CD / 128, M / 128), dim3(256), 0, stream>>>(
            hb, wbuf, yb, W[9] + l * CD, M, CD, CINTER, CINTER, CINTER, CD,
            S - 1, (long)CINTER * CD, zp);
      else
        gemm2_k<3, false><<<dim3(CD / 128, M / 128), dim3(256), 0, stream>>>(
            hb, wbuf, yb, W[9] + l * CD, M, CD, CINTER, CINTER, CINTER, CD,
            S - 1, (long)CINTER * CD, zp);
      ln_res_k<<<dim3((unsigned)M), dim3(256), 0, stream>>>(x1, yb, W[10] + l * CD, W[11] + l * CD, x);
    }
  };

  run_stack(xe, CT, Me, tlen, ew);

  cumsum_k<<<dim3(1), dim3(64), 0, stream>>>(dur, cums);
  regulate_k<<<dim3((unsigned)(CB * CMEL)), dim3(256), 0, stream>>>(xe, cums, mlen, xd);

  run_stack(xd, CMEL, Md, mlen, dw);

  // final projection, transposed f32 store straight to d_out
  cvtT(out_w, wbuf, CD, COUT, 1);
  gemmF_k<128, 128><<<dim3(1, Md / 128), dim3(256), 0, stream>>>(
      xd, wbuf, (float*)d_out, out_b, Md, COUT, CD, CD, CD, zp);
}

// Round 7
// 2621.376 us; speedup vs baseline: 1.1866x; 1.0259x over previous
//
#include <hip/hip_runtime.h>

typedef unsigned short u16;
typedef short short8 __attribute__((ext_vector_type(8)));
typedef float floatx4 __attribute__((ext_vector_type(4)));

static constexpr int CB = 16, CT = 256, CMEL = 1024, CD = 512, CH = 8, CDH = 64, CL = 4;
static constexpr int CINTER = 2048, COUT = 80;
static constexpr int CQKV = 3 * CH * CDH;   // 1536

static __device__ __forceinline__ float bf2f(u16 u) {
  union { unsigned u; float f; } v; v.u = ((unsigned)u) << 16; return v.f;
}
static __device__ __forceinline__ u16 f2bf(float f) {  // RNE; inputs finite
  union { float f; unsigned u; } v; v.f = f;
  unsigned r = v.u + 0x7fffu + ((v.u >> 16) & 1u);
  return (u16)(r >> 16);
}

// async global->LDS, 16B per lane; LDS dest = wave-uniform base + lane*16 (m104/m108)
static __device__ __forceinline__ void gld16(const u16* g, u16* lds) {
  __builtin_amdgcn_global_load_lds((const __attribute__((address_space(1))) void*)g,
                                   (__attribute__((address_space(3))) void*)lds, 16, 0, 0);
}

// ===========================================================================
// gemm2_k: 128x128-tile, 4-wave (256 thr) bf16 MFMA GEMM with folded conv taps.
// Proven baseline structure (R0, 2651 us). Used for ALL stacked GEMMs again:
// R6 measured the 2-phase variant (gemm2p) at identical MfmaUtil (37%) and
// slightly worse time -> staging latency was never the limiter (LDS read BW
// is: 96KB/block-K-step @256B/cyc = 384cyc vs 240cyc MFMA). Reverted.
// ===========================================================================
template<int NT, bool RELU>
__global__ __launch_bounds__(256)
void gemm2_k(const u16* __restrict__ A, const u16* __restrict__ Bm,
             u16* __restrict__ Cm, const float* __restrict__ bias,
             int M, int N, int K, int lda, int ldb, int ldc,
             int Sm1, long tapStrideB, const u16* __restrict__ zp)
{
  constexpr int BM = 128, BN = 128;
  constexpr int H = (NT == 3) ? 8 : 0;
  constexpr int AR = BM + 2 * H;           // 144 or 128
  __shared__ u16 As[AR * 32];
  __shared__ u16 Bs[NT * BN * 32];

  const int t = threadIdx.x;
  const int lane = t & 63;
  const int wave = t >> 6;                 // 0..3
  const int wrow = wave >> 1;              // 0..1
  const int wcol = wave & 1;               // 0..1
  const int bn0 = blockIdx.x * BN;
  const int bm0 = blockIdx.y * BM;

  floatx4 acc[4][4];
#pragma unroll
  for (int i = 0; i < 4; ++i)
#pragma unroll
    for (int j = 0; j < 4; ++j) acc[i][j] = (floatx4){0.f, 0.f, 0.f, 0.f};

  const int rsub = lane >> 2;
  const int g8 = (((lane & 3) ^ ((lane >> 3) & 3)) << 3);

  // ---- A chunk pointers: chunks {wave, wave+4} (+ chunk 8 by wave 0, NT=3)
  const u16* aP0; const u16* aP1; const u16* aP2 = nullptr;
  {
    int gg0 = bm0 - H + wave * 16 + rsub;
    int gg1 = bm0 - H + (wave + 4) * 16 + rsub;
    aP0 = ((NT == 1) || ((unsigned)gg0 < (unsigned)M)) ? A + (long)gg0 * lda + g8 : nullptr;
    aP1 = ((NT == 1) || ((unsigned)gg1 < (unsigned)M)) ? A + (long)gg1 * lda + g8 : nullptr;
    if (NT == 3 && wave == 0) {
      int gg2 = bm0 - H + 128 + rsub;      // chunk 8
      aP2 = ((unsigned)gg2 < (unsigned)M) ? A + (long)gg2 * lda + g8 : nullptr;
    }
  }
  const int aL0 = wave * 512, aL1 = (wave + 4) * 512, aL2 = 8 * 512;

  // ---- B chunk pointers: per tap, chunks {wave, wave+4}
  const u16* bP[NT][2]; int bL[NT][2];
#pragma unroll
  for (int i = 0; i < NT; ++i)
#pragma unroll
    for (int j = 0; j < 2; ++j) {
      int r = (wave + j * 4) * 16 + rsub;
      bP[i][j] = Bm + (long)i * tapStrideB + (long)(bn0 + r) * ldb + g8;
      bL[i][j] = (i * BN + (wave + j * 4) * 16) * 32;
    }

  const int q = lane >> 4, fm = lane & 15;
  const int swzB = (q ^ ((fm >> 1) & 3)) << 3;
  int swzA[NT];
  bool mv[NT][4];
#pragma unroll
  for (int tap = 0; tap < NT; ++tap) {
    const int dlt = tap - ((NT == 3) ? 1 : 0);
    swzA[tap] = (q ^ ((((H + dlt + fm) & 15) >> 1) & 3)) << 3;
#pragma unroll
    for (int i = 0; i < 4; ++i) {
      int s = (bm0 + wrow * 64 + i * 16 + fm) & Sm1;
      mv[tap][i] = ((unsigned)(s + dlt) <= (unsigned)Sm1);
    }
  }
  const short8 zero8 = {};

  for (int k0 = 0; k0 < K; k0 += 32) {
    gld16(aP0 ? aP0 + k0 : zp, &As[aL0]);
    gld16(aP1 ? aP1 + k0 : zp, &As[aL1]);
    if (NT == 3 && wave == 0) gld16(aP2 ? aP2 + k0 : zp, &As[aL2]);
#pragma unroll
    for (int i = 0; i < NT; ++i)
#pragma unroll
      for (int j = 0; j < 2; ++j) gld16(bP[i][j] + k0, &Bs[bL[i][j]]);
    __syncthreads();

#pragma unroll
    for (int tap = 0; tap < NT; ++tap) {
      const int dlt = tap - ((NT == 3) ? 1 : 0);
      short8 af[4], bfr[4];
#pragma unroll
      for (int i = 0; i < 4; ++i) {
        af[i] = *(const short8*)&As[(wrow * 64 + i * 16 + fm + H + dlt) * 32 + swzA[tap]];
        if (NT == 3 && !mv[tap][i]) af[i] = zero8;
      }
#pragma unroll
      for (int j = 0; j < 4; ++j)
        bfr[j] = *(const short8*)&Bs[(tap * BN + wcol * 64 + j * 16 + fm) * 32 + swzB];
#pragma unroll
      for (int i = 0; i < 4; ++i)
#pragma unroll
        for (int j = 0; j < 4; ++j)
          acc[i][j] = __builtin_amdgcn_mfma_f32_16x16x32_bf16(af[i], bfr[j], acc[i][j], 0, 0, 0);
    }
    __syncthreads();
  }

  const int rbase = bm0 + wrow * 64 + ((lane >> 4) << 2);
  const int cbase = bn0 + wcol * 64 + fm;
#pragma unroll
  for (int j = 0; j < 4; ++j) {
    int col = cbase + j * 16;              // N multiple of 128 for all gemm2 uses
    float bv = bias ? bias[col] : 0.f;
#pragma unroll
    for (int i = 0; i < 4; ++i) {
#pragma unroll
      for (int r = 0; r < 4; ++r) {
        int row = rbase + i * 16 + r;
        float v = acc[i][j][r] + bv;
        if (RELU) v = fmaxf(v, 0.f);
        Cm[(long)row * ldc + col] = f2bf(v);
      }
    }
  }
}

// ===========================================================================
// attn_k: fused flash attention (unchanged).
// ===========================================================================
__global__ __launch_bounds__(512)
void attn_k(const u16* __restrict__ qkv, const u16* __restrict__ vt,
            u16* __restrict__ ctx, const int* __restrict__ lens, int S)
{
  __shared__ __attribute__((aligned(16))) u16 Ks[2][128 * 32];   // [dh-step][kv][32 dh]
  __shared__ __attribute__((aligned(16))) u16 Vts[4][64 * 32];   // [kv-step][dh][32 kv]
  __shared__ __attribute__((aligned(16))) u16 Ps[8][16][136];    // per-wave P [q16][kv128]+pad

  const int t = threadIdx.x, lane = t & 63, w = t >> 6;
  const int bh = blockIdx.y, b = bh >> 3, h = bh & 7;
  const int q0 = blockIdx.x * 128;
  const int len = lens[b];
  const int fm = lane & 15, quad = lane >> 4;
  const int swz8 = ((quad ^ ((fm >> 1) & 3)) << 3);
  const int rsub = lane >> 2;
  const int g8 = (((lane & 3) ^ ((lane >> 3) & 3)) << 3);

  // Q B-frags in registers: B[n=q=fm][k=dh]
  const int qrow = q0 + w * 16 + fm;
  short8 bq[2];
  bq[0] = *(const short8*)&qkv[(long)(b * S + qrow) * CQKV + h * 64 + quad * 8];
  bq[1] = *(const short8*)&qkv[(long)(b * S + qrow) * CQKV + h * 64 + 32 + quad * 8];

  // K staging: 16 chunks (ks in {0,1} x rg in 0..7); wave w takes (w&1, w>>1) and (w&1, w>>1+4)
  const int ksW = w & 1, rgA = w >> 1, rgB = (w >> 1) + 4;
  const u16* kBaseA = qkv + ((long)b * S + rgA * 16 + rsub) * CQKV + CD + h * 64 + ksW * 32 + g8;
  const u16* kBaseB = qkv + ((long)b * S + rgB * 16 + rsub) * CQKV + CD + h * 64 + ksW * 32 + g8;
  u16* kDstA = &Ks[ksW][rgA * 512];
  u16* kDstB = &Ks[ksW][rgB * 512];
  // Vt staging: 16 chunks c = kvs*4 + dhc; wave w takes c = 2w, 2w+1
  const int kvs0 = (2 * w) >> 2, dhc0 = (2 * w) & 3;
  const int kvs1 = (2 * w + 1) >> 2, dhc1 = (2 * w + 1) & 3;
  const u16* vBase0 = vt + ((long)bh * 64 + dhc0 * 16 + rsub) * S + kvs0 * 32 + g8;
  const u16* vBase1 = vt + ((long)bh * 64 + dhc1 * 16 + rsub) * S + kvs1 * 32 + g8;
  u16* vDst0 = &Vts[kvs0][dhc0 * 512];
  u16* vDst1 = &Vts[kvs1][dhc1 * 512];

  floatx4 acc_o[4];
#pragma unroll
  for (int j = 0; j < 4; ++j) acc_o[j] = (floatx4){0.f, 0.f, 0.f, 0.f};
  float m = -1e30f, l = 0.f;

  for (int kv0 = 0; kv0 < S; kv0 += 128) {
    __syncthreads();                      // previous-iter tile reads complete
    gld16(kBaseA + (long)kv0 * CQKV, kDstA);
    gld16(kBaseB + (long)kv0 * CQKV, kDstB);
    gld16(vBase0 + kv0, vDst0);
    gld16(vBase1 + kv0, vDst1);
    __syncthreads();                      // staging visible

    // ---- S^T tile: M=kv 128 (8 frags), N=q 16, K=dh 64 (2 steps)
    floatx4 sa[8];
#pragma unroll
    for (int i = 0; i < 8; ++i) sa[i] = (floatx4){0.f, 0.f, 0.f, 0.f};
#pragma unroll
    for (int ks = 0; ks < 2; ++ks) {
#pragma unroll
      for (int mi = 0; mi < 8; ++mi) {
        short8 ak = *(const short8*)&Ks[ks][(mi * 16 + fm) * 32 + swz8];
        sa[mi] = __builtin_amdgcn_mfma_f32_16x16x32_bf16(ak, bq[ks], sa[mi], 0, 0, 0);
      }
    }

    // ---- online softmax (per q-row = lane&15; kv rows = mi*16 + quad*4 + r)
    float p[8][4], tm = -1e30f;
#pragma unroll
    for (int mi = 0; mi < 8; ++mi)
#pragma unroll
      for (int r = 0; r < 4; ++r) {
        int kvg = kv0 + mi * 16 + quad * 4 + r;
        float v = (kvg <= len) ? sa[mi][r] * 0.125f : -1e30f;
        p[mi][r] = v; tm = fmaxf(tm, v);
      }
    tm = fmaxf(tm, __shfl_xor(tm, 16));
    tm = fmaxf(tm, __shfl_xor(tm, 32));
    const float mnew = fmaxf(m, tm);
    const float al = __expf(m - mnew);
    float ts = 0.f;
#pragma unroll
    for (int mi = 0; mi < 8; ++mi)
#pragma unroll
      for (int r = 0; r < 4; ++r) { float e = __expf(p[mi][r] - mnew); p[mi][r] = e; ts += e; }
    ts += __shfl_xor(ts, 16);
    ts += __shfl_xor(ts, 32);
    l = l * al + ts; m = mnew;
    float al4[4];
#pragma unroll
    for (int r = 0; r < 4; ++r) al4[r] = __shfl(al, ((lane >> 4) << 2) + r, 64);
#pragma unroll
    for (int j = 0; j < 4; ++j)
#pragma unroll
      for (int r = 0; r < 4; ++r) acc_o[j][r] *= al4[r];

    // ---- P -> LDS (wave-private): Ps[w][q=fm][kv = mi*16+quad*4+r]
#pragma unroll
    for (int mi = 0; mi < 8; ++mi) {
      unsigned u01 = (unsigned)f2bf(p[mi][0]) | ((unsigned)f2bf(p[mi][1]) << 16);
      unsigned u23 = (unsigned)f2bf(p[mi][2]) | ((unsigned)f2bf(p[mi][3]) << 16);
      *(uint2*)&Ps[w][fm][mi * 16 + quad * 4] = make_uint2(u01, u23);
    }

    // ---- O += P @ V: M=q 16, N=dh 64 (4 frags), K=kv 128 (4 steps)
#pragma unroll
    for (int kvs = 0; kvs < 4; ++kvs) {
      short8 ap = *(const short8*)&Ps[w][fm][kvs * 32 + quad * 8];
#pragma unroll
      for (int nj = 0; nj < 4; ++nj) {
        short8 bv = *(const short8*)&Vts[kvs][(nj * 16 + fm) * 32 + swz8];
        acc_o[nj] = __builtin_amdgcn_mfma_f32_16x16x32_bf16(ap, bv, acc_o[nj], 0, 0, 0);
      }
    }
  }

  // ---- epilogue: O[q][dh] / l
  float li4[4];
#pragma unroll
  for (int r = 0; r < 4; ++r) li4[r] = 1.f / __shfl(l, ((lane >> 4) << 2) + r, 64);
#pragma unroll
  for (int nj = 0; nj < 4; ++nj)
#pragma unroll
    for (int r = 0; r < 4; ++r) {
      int qr = q0 + w * 16 + quad * 4 + r;
      ctx[(long)(b * S + qr) * CD + h * 64 + nj * 16 + fm] = f2bf(acc_o[nj][r] * li4[r]);
    }
}

// ---------------------------------------------------------------------------
// Final-projection GEMM (N=80), f32 transposed store to d_out.
// ---------------------------------------------------------------------------
template<int BM, int BN>
__global__ __launch_bounds__(256)
void gemmF_k(const u16* __restrict__ A, const u16* __restrict__ Bm,
             float* __restrict__ Cm, const float* __restrict__ bias,
             int M, int N, int K, int lda, int ldb,
             const u16* __restrict__ zp)
{
  __shared__ u16 As[BM * 32];
  __shared__ u16 Bs[BN * 32];

  const int t = threadIdx.x;
  const int lane = t & 63;
  const int wave = t >> 6;
  constexpr int WCOLS = BN / 64;
  const int wrow = wave / WCOLS;
  const int wcol = wave % WCOLS;
  const int bn0 = blockIdx.x * BN;
  const int bm0 = blockIdx.y * BM;

  floatx4 acc[4][4];
#pragma unroll
  for (int i = 0; i < 4; ++i)
#pragma unroll
    for (int j = 0; j < 4; ++j) acc[i][j] = (floatx4){0.f, 0.f, 0.f, 0.f};

  const int rsub = lane >> 2;
  const int g8 = (((lane & 3) ^ ((lane >> 3) & 3)) << 3);
  constexpr int PA = BM / 64, PB = BN / 64;

  const int q = lane >> 4, fm = lane & 15;
  const int swz8 = ((q ^ ((fm >> 1) & 3)) << 3);

  const u16* aP[PA]; const u16* bP[PB];
#pragma unroll
  for (int p = 0; p < PA; ++p)
    aP[p] = A + (long)(bm0 + p * 64 + wave * 16 + rsub) * lda + g8;
#pragma unroll
  for (int p = 0; p < PB; ++p) {
    int r = p * 64 + wave * 16 + rsub;
    bP[p] = ((bn0 + r) < N) ? (Bm + (long)(bn0 + r) * ldb + g8) : nullptr;
  }

  for (int k0 = 0; k0 < K; k0 += 32) {
#pragma unroll
    for (int p = 0; p < PA; ++p)
      gld16(aP[p] + k0, &As[(p * 64 + wave * 16) * 32]);
#pragma unroll
    for (int p = 0; p < PB; ++p)
      gld16(bP[p] ? bP[p] + k0 : zp, &Bs[(p * 64 + wave * 16) * 32]);
    __syncthreads();

    short8 af[4], bfr[4];
#pragma unroll
    for (int i = 0; i < 4; ++i)
      af[i] = *(const short8*)&As[(wrow * 64 + i * 16 + fm) * 32 + swz8];
#pragma unroll
    for (int j = 0; j < 4; ++j)
      bfr[j] = *(const short8*)&Bs[(wcol * 64 + j * 16 + fm) * 32 + swz8];
#pragma unroll
    for (int i = 0; i < 4; ++i)
#pragma unroll
      for (int j = 0; j < 4; ++j)
        acc[i][j] = __builtin_amdgcn_mfma_f32_16x16x32_bf16(af[i], bfr[j], acc[i][j], 0, 0, 0);
    __syncthreads();
  }

  const int rbase = bm0 + wrow * 64 + ((lane >> 4) << 2);
  const int cbase = bn0 + wcol * 64 + (lane & 15);
#pragma unroll
  for (int j = 0; j < 4; ++j) {
    int col = cbase + j * 16;
    if (col >= N) continue;
    float bv = bias ? bias[col] : 0.f;
#pragma unroll
    for (int i = 0; i < 4; ++i) {
#pragma unroll
      for (int r = 0; r < 4; ++r) {
        int row = rbase + i * 16 + r;
        Cm[((long)(row >> 10) * COUT + col) * CMEL + (row & 1023)] = acc[i][j][r] + bv;
      }
    }
  }
}

// ---------------------------------------------------------------------------
// W [tap][K][N] f32 -> WT [tap][N][K] bf16 (LDS-tiled 32x32 transpose)
__global__ void cvt_t_k(const float* __restrict__ src, u16* __restrict__ dst, int K, int N)
{
  const int tap = blockIdx.z;
  const int n0 = blockIdx.x * 32, k0 = blockIdx.y * 32;
  __shared__ float tile[32][33];
  const int t = threadIdx.x;
  const int c = t & 31, rr = t >> 5;
  const float* s = src + (long)tap * K * N;
  u16* d = dst + (long)tap * K * N;
#pragma unroll
  for (int i = 0; i < 4; ++i) {
    int k = k0 + rr + i * 8, n = n0 + c;
    tile[rr + i * 8][c] = (k < K && n < N) ? s[(long)k * N + n] : 0.f;
  }
  __syncthreads();
#pragma unroll
  for (int i = 0; i < 4; ++i) {
    int n = n0 + rr + i * 8, k = k0 + c;
    if (n < N && k < K) d[(long)n * K + k] = f2bf(tile[c][rr + i * 8]);
  }
}

// vt[(b*CH+h)*64 + d][S] = qkv[(b*S+s)*CQKV + 2*CD + h*64 + d]
__global__ void vtr_k(const u16* __restrict__ qkv, u16* __restrict__ vt, int S)
{
  const int s0 = blockIdx.x * 64;
  const int bh = blockIdx.y;
  const int b = bh >> 3, h = bh & 7;
  __shared__ u16 tile[64][65];
  const int t = threadIdx.x;
  const int wave = t >> 6, lane = t & 63;
#pragma unroll
  for (int i = 0; i < 16; ++i) {
    int sl = wave * 16 + i;
    tile[sl][lane] = qkv[(long)(b * S + s0 + sl) * CQKV + 2 * CD + h * 64 + lane];
  }
  __syncthreads();
  const int dl = t >> 2, sc4 = (t & 3) << 4;
  u16* dstp = vt + ((long)bh * 64 + dl) * S + s0 + sc4;
  short8 v0, v1;
#pragma unroll
  for (int j = 0; j < 8; ++j) { v0[j] = (short)tile[sc4 + j][dl]; v1[j] = (short)tile[sc4 + 8 + j][dl]; }
  *(short8*)dstp = v0;
  *(short8*)(dstp + 8) = v1;
}

__global__ void fill_k(float* __restrict__ o, int n, float v)
{
  int i = blockIdx.x * 256 + threadIdx.x;
  if (i < n) o[i] = v;
}

// x[b,t,:] = bf16( 2*emb[tok] + pos[b] )   (reference quirk: pos indexed by BATCH b)
__global__ void embed_k(const int* __restrict__ tok, const float* __restrict__ emb,
                        u16* __restrict__ X)
{
  const long idx = (long)blockIdx.x * 256 + threadIdx.x;
  const int d = (int)(idx & (CD - 1));
  const int m = (int)(idx >> 9);
  const int b = m >> 8;
  const float e = emb[(long)tok[m] * CD + d];
  const int i2 = d >> 1;
  const float den = __expf(-(float)(2 * i2) * (9.210340371976184f / 512.f));
  const float ang = (float)b * den;
  const float p = (d & 1) ? __cosf(ang) : __sinf(ang);
  X[idx] = f2bf(2.f * e + p);
}

// ===========================================================================
// ln_res_k (R12): O = LN(X + Y) * g + b.  Wave-per-row, barrier-free.
// Old version: 256 thr/row, two 8-level LDS tree reductions = 18 __syncthreads
// per 512-elem row, scalar 2B loads. New: one wave per row (4 rows/block),
// short8 (16B) vectorized loads, __shfl_xor butterfly reductions (wave-
// synchronous, zero barriers, zero LDS). BW floor per dec call ~50MB -> ~8us.
// Grid: M/4 blocks x 256 thr.  M % 4 == 0 at both call sites.
// ===========================================================================
__global__ __launch_bounds__(256)
void ln_res_k(const u16* __restrict__ X, const u16* __restrict__ Y,
              const float* __restrict__ g, const float* __restrict__ bta,
              u16* __restrict__ O)
{
  const int w = threadIdx.x >> 6, lane = threadIdx.x & 63;
  const long m = (long)blockIdx.x * 4 + w;
  const long base = m * CD + lane * 8;
  const short8 xv = *(const short8*)&X[base];
  const short8 yv = *(const short8*)&Y[base];
  float v[8]; float s = 0.f;
#pragma unroll
  for (int j = 0; j < 8; ++j) { v[j] = bf2f((u16)xv[j]) + bf2f((u16)yv[j]); s += v[j]; }
#pragma unroll
  for (int o = 1; o < 64; o <<= 1) s += __shfl_xor(s, o);
  const float mean = s * (1.f / 512.f);
  float qs = 0.f;
#pragma unroll
  for (int j = 0; j < 8; ++j) { v[j] -= mean; qs += v[j] * v[j]; }
#pragma unroll
  for (int o = 1; o < 64; o <<= 1) qs += __shfl_xor(qs, o);
  const float rstd = rsqrtf(qs * (1.f / 512.f) + 1e-5f);
  const float4 g0 = *(const float4*)&g[lane * 8];
  const float4 g1 = *(const float4*)&g[lane * 8 + 4];
  const float4 b0 = *(const float4*)&bta[lane * 8];
  const float4 b1 = *(const float4*)&bta[lane * 8 + 4];
  short8 ov;
  ov[0] = (short)f2bf(v[0] * rstd * g0.x + b0.x);
  ov[1] = (short)f2bf(v[1] * rstd * g0.y + b0.y);
  ov[2] = (short)f2bf(v[2] * rstd * g0.z + b0.z);
  ov[3] = (short)f2bf(v[3] * rstd * g0.w + b0.w);
  ov[4] = (short)f2bf(v[4] * rstd * g1.x + b1.x);
  ov[5] = (short)f2bf(v[5] * rstd * g1.y + b1.y);
  ov[6] = (short)f2bf(v[6] * rstd * g1.z + b1.z);
  ov[7] = (short)f2bf(v[7] * rstd * g1.w + b1.w);
  *(short8*)&O[base] = ov;
}

__global__ void cumsum_k(const int* __restrict__ dur, int* __restrict__ cums)
{
  int b = threadIdx.x;
  if (b < CB) {
    int s = 0;
    for (int t = 0; t < CT; ++t) { s += dur[b * CT + t]; cums[b * CT + t] = s; }
  }
}

// ===========================================================================
// regulate_k (R12): wave-per-row, short8 vectorized copy (was scalar 2B).
// Grid: CB*CMEL/4 blocks x 256 thr.
// ===========================================================================
__global__ __launch_bounds__(256)
void regulate_k(const u16* __restrict__ xe, const int* __restrict__ cums,
                const int* __restrict__ mlen, u16* __restrict__ xd)
{
  const int w = threadIdx.x >> 6, lane = threadIdx.x & 63;
  const int m = blockIdx.x * 4 + w;
  const int b = m >> 10, f = m & (CMEL - 1);
  int lo = 0, hi = CT;
  while (lo < hi) { int mid = (lo + hi) >> 1; if (cums[b * CT + mid] <= f) lo = mid + 1; else hi = mid; }
  const int idx = min(lo, CT - 1);
  const bool keep = (f <= mlen[b]);
  short8 val = {};
  if (keep) val = *(const short8*)&xe[((long)b * CT + idx) * CD + lane * 8];
  *(short8*)&xd[(long)m * CD + lane * 8] = val;
}

// ---------------------------------------------------------------------------
extern "C" void kernel_launch(void* const* d_in, const int* in_sizes, int n_in,
                              void* d_out, int out_size, void* d_ws, size_t ws_size,
                              hipStream_t stream)
{
  (void)in_sizes; (void)n_in;
  const int*   tokens = (const int*)d_in[0];
  const int*   tlen   = (const int*)d_in[1];
  const int*   mlen   = (const int*)d_in[2];
  const int*   dur    = (const int*)d_in[3];
  const float* emb    = (const float*)d_in[5];
  const float* ew[12]; const float* dw[12];
  for (int i = 0; i < 12; ++i) { ew[i] = (const float*)d_in[6 + i]; dw[i] = (const float*)d_in[18 + i]; }
  const float* out_w = (const float*)d_in[30];
  const float* out_b = (const float*)d_in[31];

  const int Me = CB * CT;       // 4096
  const int Md = CB * CMEL;     // 16384

  const size_t SZ_ZP   = 256;
  const size_t SZ_WBUF = (size_t)3 * CD * CINTER * 2;
  const size_t SZ_XE   = (size_t)Me * CD * 2;
  const size_t SZ_XD   = (size_t)Md * CD * 2;     // x, x1(ctx), yb(vt)
  const size_t SZ_QKV  = (size_t)Md * CQKV * 2;   // 50.3 MB
  const size_t SZ_HB   = (size_t)Md * CINTER * 2; // 67.1 MB
  const size_t SZ_CUMS = (size_t)CB * CT * 4;
  auto al = [](size_t b) { return (b + 255) & ~(size_t)255; };
  size_t U = al(SZ_QKV) > al(SZ_HB) ? al(SZ_QKV) : al(SZ_HB);
  size_t total = al(SZ_ZP) + al(SZ_WBUF) + al(SZ_XE) + 3 * al(SZ_XD) + U + al(SZ_CUMS);
  if (total > ws_size) {
    fill_k<<<dim3((unsigned)((out_size + 255) / 256)), dim3(256), 0, stream>>>(
        (float*)d_out, out_size, 1000.0f);
    return;
  }

  char* p = (char*)d_ws;
  auto take = [&](size_t bytes) { char* r = p; p += al(bytes); return r; };
  u16*  zp   = (u16*)take(SZ_ZP);
  u16*  wbuf = (u16*)take(SZ_WBUF);
  u16*  xe   = (u16*)take(SZ_XE);
  u16*  xd   = (u16*)take(SZ_XD);
  u16*  x1   = (u16*)take(SZ_XD);   // also ctx during attention
  u16*  yb   = (u16*)take(SZ_XD);   // also vt during attention
  char* U0   = take(U);
  u16*  qkvB = (u16*)U0;
  u16*  hb   = (u16*)U0;
  int* cums = (int*)take(SZ_CUMS);

  hipMemsetAsync(zp, 0, SZ_ZP, stream);

  auto cvtT = [&](const float* s, u16* d, int K, int N, int taps) {
    cvt_t_k<<<dim3((unsigned)((N + 31) / 32), (unsigned)((K + 31) / 32), (unsigned)taps),
              dim3(256), 0, stream>>>(s, d, K, N);
  };

  embed_k<<<dim3((unsigned)((long)Me * CD / 256)), dim3(256), 0, stream>>>(tokens, emb, xe);

  auto run_stack = [&](u16* x, int S, int M, const int* lens, const float* const* W) {
    u16* vt = yb;
    for (int l = 0; l < CL; ++l) {
      // qkv = x @ Wqkv + b
      cvtT(W[0] + (long)l * CD * CQKV, wbuf, CD, CQKV, 1);
      gemm2_k<1, false><<<dim3(CQKV / 128, M / 128), dim3(256), 0, stream>>>(
          x, wbuf, qkvB, W[1] + l * CQKV, M, CQKV, CD, CD, CD, CQKV, S - 1, 0, zp);
      // V^T
      vtr_k<<<dim3((unsigned)(S / 64), (unsigned)(CB * CH)), dim3(256), 0, stream>>>(qkvB, vt, S);
      // fused attention -> ctx (= x1)
      attn_k<<<dim3((unsigned)(S / 128), (unsigned)(CB * CH)), dim3(512), 0, stream>>>(
          qkvB, vt, x1, lens, S);
      // proj: ctx @ Wo + bo -> yb
      cvtT(W[2] + (long)l * CD * CD, wbuf, CD, CD, 1);
      gemm2_k<1, false><<<dim3(CD / 128, M / 128), dim3(256), 0, stream>>>(
          x1, wbuf, yb, W[3] + l * CD, M, CD, CD, CD, CD, CD, S - 1, 0, zp);
      ln_res_k<<<dim3((unsigned)(M / 4)), dim3(256), 0, stream>>>(
          x, yb, W[4] + l * CD, W[5] + l * CD, x1);
      // conv1 (3-tap) + relu
      cvtT(W[6] + (long)l * 3 * CD * CINTER, wbuf, CD, CINTER, 3);
      gemm2_k<3, true><<<dim3(CINTER / 128, M / 128), dim3(256), 0, stream>>>(
          x1, wbuf, hb, W[7] + l * CINTER, M, CINTER, CD, CD, CD, CINTER,
          S - 1, (long)CD * CINTER, zp);
      // conv2 (3-tap)
      cvtT(W[8] + (long)l * 3 * CINTER * CD, wbuf, CINTER, CD, 3);
      gemm2_k<3, false><<<dim3(CD / 128, M / 128), dim3(256), 0, stream>>>(
          hb, wbuf, yb, W[9] + l * CD, M, CD, CINTER, CINTER, CINTER, CD,
          S - 1, (long)CINTER * CD, zp);
      ln_res_k<<<dim3((unsigned)(M / 4)), dim3(256), 0, stream>>>(
          x1, yb, W[10] + l * CD, W[11] + l * CD, x);
    }
  };

  run_stack(xe, CT, Me, tlen, ew);

  cumsum_k<<<dim3(1), dim3(64), 0, stream>>>(dur, cums);
  regulate_k<<<dim3((unsigned)(CB * CMEL / 4)), dim3(256), 0, stream>>>(xe, cums, mlen, xd);

  run_stack(xd, CMEL, Md, mlen, dw);

  // final projection, transposed f32 store straight to d_out
  cvtT(out_w, wbuf, CD, COUT, 1);
  gemmF_k<128, 128><<<dim3(1, Md / 128), dim3(256), 0, stream>>>(
      xd, wbuf, (float*)d_out, out_b, Md, COUT, CD, CD, CD, zp);
}

// Round 8
// 2494.315 us; speedup vs baseline: 1.2470x; 1.0509x over previous
//
#include <hip/hip_runtime.h>

typedef unsigned short u16;
typedef short short8 __attribute__((ext_vector_type(8)));
typedef float floatx4 __attribute__((ext_vector_type(4)));

static constexpr int CB = 16, CT = 256, CMEL = 1024, CD = 512, CH = 8, CDH = 64, CL = 4;
static constexpr int CINTER = 2048, COUT = 80;
static constexpr int CQKV = 3 * CH * CDH;   // 1536

static __device__ __forceinline__ float bf2f(u16 u) {
  union { unsigned u; float f; } v; v.u = ((unsigned)u) << 16; return v.f;
}
static __device__ __forceinline__ u16 f2bf(float f) {  // RNE; inputs finite
  union { float f; unsigned u; } v; v.f = f;
  unsigned r = v.u + 0x7fffu + ((v.u >> 16) & 1u);
  return (u16)(r >> 16);
}

// async global->LDS, 16B per lane; LDS dest = wave-uniform base + lane*16 (m104/m108)
static __device__ __forceinline__ void gld16(const u16* g, u16* lds) {
  __builtin_amdgcn_global_load_lds((const __attribute__((address_space(1))) void*)g,
                                   (__attribute__((address_space(3))) void*)lds, 16, 0, 0);
}

// ===========================================================================
// gemm2_k: BMTx128-tile, 4-wave (256 thr) bf16 MFMA GEMM with folded conv taps.
// Proven R0 structure (888 TF = m97-structure ceiling; R6/R7 proved drain
// placement/barrier count don't move it). R13: BMT template param added —
// BMT=64 doubles the grid for the under-filled encoder conv2/proj (128 blocks
// on 256 CUs = half chip idle). Fragment/halo/swizzle math unchanged; only
// row-frags per wave (FR=BMT/32) and the A-chunk table scale.
// ===========================================================================
template<int BMT, int NT, bool RELU>
__global__ __launch_bounds__(256)
void gemm2_k(const u16* __restrict__ A, const u16* __restrict__ Bm,
             u16* __restrict__ Cm, const float* __restrict__ bias,
             int M, int N, int K, int lda, int ldb, int ldc,
             int Sm1, long tapStrideB, const u16* __restrict__ zp)
{
  constexpr int BM = BMT, BN = 128;
  constexpr int H = (NT == 3) ? 8 : 0;
  constexpr int AR = BM + 2 * H;           // 144/128 (BM=128) or 80/64 (BM=64)
  constexpr int ACH = AR / 16;             // A chunks of 16 rows: 9/8/5/4
  constexpr int FR = BM / 32;              // row frags per wave: 4 or 2
  __shared__ u16 As[AR * 32];
  __shared__ u16 Bs[NT * BN * 32];

  const int t = threadIdx.x;
  const int lane = t & 63;
  const int wave = t >> 6;                 // 0..3
  const int wrow = wave >> 1;              // 0..1
  const int wcol = wave & 1;               // 0..1
  const int bn0 = blockIdx.x * BN;
  const int bm0 = blockIdx.y * BM;

  floatx4 acc[FR][4];
#pragma unroll
  for (int i = 0; i < FR; ++i)
#pragma unroll
    for (int j = 0; j < 4; ++j) acc[i][j] = (floatx4){0.f, 0.f, 0.f, 0.f};

  const int rsub = lane >> 2;
  const int g8 = (((lane & 3) ^ ((lane >> 3) & 3)) << 3);

  // ---- A chunk table: wave handles chunks {wave, wave+4, wave+8} ∩ [0,ACH)
  const u16* aP[3]; int aL[3]; bool aU[3];
#pragma unroll
  for (int s = 0; s < 3; ++s) {
    const int c = wave + 4 * s;
    aU[s] = (c < ACH);
    aL[s] = c * 512;
    aP[s] = nullptr;
    if (aU[s]) {
      int gg = bm0 - H + c * 16 + rsub;
      aP[s] = ((NT == 1) || ((unsigned)gg < (unsigned)M)) ? A + (long)gg * lda + g8 : nullptr;
    }
  }

  // ---- B chunk pointers: per tap, chunks {wave, wave+4}
  const u16* bP[NT][2]; int bL[NT][2];
#pragma unroll
  for (int i = 0; i < NT; ++i)
#pragma unroll
    for (int j = 0; j < 2; ++j) {
      int r = (wave + j * 4) * 16 + rsub;
      bP[i][j] = Bm + (long)i * tapStrideB + (long)(bn0 + r) * ldb + g8;
      bL[i][j] = (i * BN + (wave + j * 4) * 16) * 32;
    }

  const int q = lane >> 4, fm = lane & 15;
  const int swzB = (q ^ ((fm >> 1) & 3)) << 3;
  int swzA[NT];
  bool mv[NT][FR];
#pragma unroll
  for (int tap = 0; tap < NT; ++tap) {
    const int dlt = tap - ((NT == 3) ? 1 : 0);
    swzA[tap] = (q ^ ((((H + dlt + fm) & 15) >> 1) & 3)) << 3;
#pragma unroll
    for (int i = 0; i < FR; ++i) {
      int s = (bm0 + wrow * (BM / 2) + i * 16 + fm) & Sm1;
      mv[tap][i] = ((unsigned)(s + dlt) <= (unsigned)Sm1);
    }
  }
  const short8 zero8 = {};

  for (int k0 = 0; k0 < K; k0 += 32) {
#pragma unroll
    for (int s = 0; s < 3; ++s)
      if (aU[s]) gld16(aP[s] ? aP[s] + k0 : zp, &As[aL[s]]);
#pragma unroll
    for (int i = 0; i < NT; ++i)
#pragma unroll
      for (int j = 0; j < 2; ++j) gld16(bP[i][j] + k0, &Bs[bL[i][j]]);
    __syncthreads();

#pragma unroll
    for (int tap = 0; tap < NT; ++tap) {
      const int dlt = tap - ((NT == 3) ? 1 : 0);
      short8 af[FR], bfr[4];
#pragma unroll
      for (int i = 0; i < FR; ++i) {
        af[i] = *(const short8*)&As[(wrow * (BM / 2) + i * 16 + fm + H + dlt) * 32 + swzA[tap]];
        if (NT == 3 && !mv[tap][i]) af[i] = zero8;
      }
#pragma unroll
      for (int j = 0; j < 4; ++j)
        bfr[j] = *(const short8*)&Bs[(tap * BN + wcol * 64 + j * 16 + fm) * 32 + swzB];
#pragma unroll
      for (int i = 0; i < FR; ++i)
#pragma unroll
        for (int j = 0; j < 4; ++j)
          acc[i][j] = __builtin_amdgcn_mfma_f32_16x16x32_bf16(af[i], bfr[j], acc[i][j], 0, 0, 0);
    }
    __syncthreads();
  }

  const int rbase = bm0 + wrow * (BM / 2) + ((lane >> 4) << 2);
  const int cbase = bn0 + wcol * 64 + fm;
#pragma unroll
  for (int j = 0; j < 4; ++j) {
    int col = cbase + j * 16;              // N multiple of 128 for all gemm2 uses
    float bv = bias ? bias[col] : 0.f;
#pragma unroll
    for (int i = 0; i < FR; ++i) {
#pragma unroll
      for (int r = 0; r < 4; ++r) {
        int row = rbase + i * 16 + r;
        float v = acc[i][j][r] + bv;
        if (RELU) v = fmaxf(v, 0.f);
        Cm[(long)row * ldc + col] = f2bf(v);
      }
    }
  }
}

// ===========================================================================
// attn_k: fused flash attention.
// R13: early-exit over fully-masked kv-tiles. Tiles with kv0 > len contribute
// exactly zero (all p = exp(-1e30-mnew) = 0, ts = 0, al = 1), so the loop
// runs only nkv = min(S, ((len>>7)+1)<<7) tiles. Block-uniform branch (len is
// per-b; whole block shares b). Decoder len in [512,1023] -> avg ~6.5/8 tiles.
// ===========================================================================
__global__ __launch_bounds__(512)
void attn_k(const u16* __restrict__ qkv, const u16* __restrict__ vt,
            u16* __restrict__ ctx, const int* __restrict__ lens, int S)
{
  __shared__ __attribute__((aligned(16))) u16 Ks[2][128 * 32];   // [dh-step][kv][32 dh]
  __shared__ __attribute__((aligned(16))) u16 Vts[4][64 * 32];   // [kv-step][dh][32 kv]
  __shared__ __attribute__((aligned(16))) u16 Ps[8][16][136];    // per-wave P [q16][kv128]+pad

  const int t = threadIdx.x, lane = t & 63, w = t >> 6;
  const int bh = blockIdx.y, b = bh >> 3, h = bh & 7;
  const int q0 = blockIdx.x * 128;
  const int len = lens[b];
  const int fm = lane & 15, quad = lane >> 4;
  const int swz8 = ((quad ^ ((fm >> 1) & 3)) << 3);
  const int rsub = lane >> 2;
  const int g8 = (((lane & 3) ^ ((lane >> 3) & 3)) << 3);

  // Q B-frags in registers: B[n=q=fm][k=dh]
  const int qrow = q0 + w * 16 + fm;
  short8 bq[2];
  bq[0] = *(const short8*)&qkv[(long)(b * S + qrow) * CQKV + h * 64 + quad * 8];
  bq[1] = *(const short8*)&qkv[(long)(b * S + qrow) * CQKV + h * 64 + 32 + quad * 8];

  // K staging: 16 chunks (ks in {0,1} x rg in 0..7); wave w takes (w&1, w>>1) and (w&1, w>>1+4)
  const int ksW = w & 1, rgA = w >> 1, rgB = (w >> 1) + 4;
  const u16* kBaseA = qkv + ((long)b * S + rgA * 16 + rsub) * CQKV + CD + h * 64 + ksW * 32 + g8;
  const u16* kBaseB = qkv + ((long)b * S + rgB * 16 + rsub) * CQKV + CD + h * 64 + ksW * 32 + g8;
  u16* kDstA = &Ks[ksW][rgA * 512];
  u16* kDstB = &Ks[ksW][rgB * 512];
  // Vt staging: 16 chunks c = kvs*4 + dhc; wave w takes c = 2w, 2w+1
  const int kvs0 = (2 * w) >> 2, dhc0 = (2 * w) & 3;
  const int kvs1 = (2 * w + 1) >> 2, dhc1 = (2 * w + 1) & 3;
  const u16* vBase0 = vt + ((long)bh * 64 + dhc0 * 16 + rsub) * S + kvs0 * 32 + g8;
  const u16* vBase1 = vt + ((long)bh * 64 + dhc1 * 16 + rsub) * S + kvs1 * 32 + g8;
  u16* vDst0 = &Vts[kvs0][dhc0 * 512];
  u16* vDst1 = &Vts[kvs1][dhc1 * 512];

  floatx4 acc_o[4];
#pragma unroll
  for (int j = 0; j < 4; ++j) acc_o[j] = (floatx4){0.f, 0.f, 0.f, 0.f};
  float m = -1e30f, l = 0.f;

  const int nkv = min(S, ((len >> 7) + 1) << 7);   // tiles with kv0 <= len
  for (int kv0 = 0; kv0 < nkv; kv0 += 128) {
    __syncthreads();                      // previous-iter tile reads complete
    gld16(kBaseA + (long)kv0 * CQKV, kDstA);
    gld16(kBaseB + (long)kv0 * CQKV, kDstB);
    gld16(vBase0 + kv0, vDst0);
    gld16(vBase1 + kv0, vDst1);
    __syncthreads();                      // staging visible

    // ---- S^T tile: M=kv 128 (8 frags), N=q 16, K=dh 64 (2 steps)
    floatx4 sa[8];
#pragma unroll
    for (int i = 0; i < 8; ++i) sa[i] = (floatx4){0.f, 0.f, 0.f, 0.f};
#pragma unroll
    for (int ks = 0; ks < 2; ++ks) {
#pragma unroll
      for (int mi = 0; mi < 8; ++mi) {
        short8 ak = *(const short8*)&Ks[ks][(mi * 16 + fm) * 32 + swz8];
        sa[mi] = __builtin_amdgcn_mfma_f32_16x16x32_bf16(ak, bq[ks], sa[mi], 0, 0, 0);
      }
    }

    // ---- online softmax (per q-row = lane&15; kv rows = mi*16 + quad*4 + r)
    float p[8][4], tm = -1e30f;
#pragma unroll
    for (int mi = 0; mi < 8; ++mi)
#pragma unroll
      for (int r = 0; r < 4; ++r) {
        int kvg = kv0 + mi * 16 + quad * 4 + r;
        float v = (kvg <= len) ? sa[mi][r] * 0.125f : -1e30f;
        p[mi][r] = v; tm = fmaxf(tm, v);
      }
    tm = fmaxf(tm, __shfl_xor(tm, 16));
    tm = fmaxf(tm, __shfl_xor(tm, 32));
    const float mnew = fmaxf(m, tm);
    const float al = __expf(m - mnew);
    float ts = 0.f;
#pragma unroll
    for (int mi = 0; mi < 8; ++mi)
#pragma unroll
      for (int r = 0; r < 4; ++r) { float e = __expf(p[mi][r] - mnew); p[mi][r] = e; ts += e; }
    ts += __shfl_xor(ts, 16);
    ts += __shfl_xor(ts, 32);
    l = l * al + ts; m = mnew;
    float al4[4];
#pragma unroll
    for (int r = 0; r < 4; ++r) al4[r] = __shfl(al, ((lane >> 4) << 2) + r, 64);
#pragma unroll
    for (int j = 0; j < 4; ++j)
#pragma unroll
      for (int r = 0; r < 4; ++r) acc_o[j][r] *= al4[r];

    // ---- P -> LDS (wave-private): Ps[w][q=fm][kv = mi*16+quad*4+r]
#pragma unroll
    for (int mi = 0; mi < 8; ++mi) {
      unsigned u01 = (unsigned)f2bf(p[mi][0]) | ((unsigned)f2bf(p[mi][1]) << 16);
      unsigned u23 = (unsigned)f2bf(p[mi][2]) | ((unsigned)f2bf(p[mi][3]) << 16);
      *(uint2*)&Ps[w][fm][mi * 16 + quad * 4] = make_uint2(u01, u23);
    }

    // ---- O += P @ V: M=q 16, N=dh 64 (4 frags), K=kv 128 (4 steps)
#pragma unroll
    for (int kvs = 0; kvs < 4; ++kvs) {
      short8 ap = *(const short8*)&Ps[w][fm][kvs * 32 + quad * 8];
#pragma unroll
      for (int nj = 0; nj < 4; ++nj) {
        short8 bv = *(const short8*)&Vts[kvs][(nj * 16 + fm) * 32 + swz8];
        acc_o[nj] = __builtin_amdgcn_mfma_f32_16x16x32_bf16(ap, bv, acc_o[nj], 0, 0, 0);
      }
    }
  }

  // ---- epilogue: O[q][dh] / l
  float li4[4];
#pragma unroll
  for (int r = 0; r < 4; ++r) li4[r] = 1.f / __shfl(l, ((lane >> 4) << 2) + r, 64);
#pragma unroll
  for (int nj = 0; nj < 4; ++nj)
#pragma unroll
    for (int r = 0; r < 4; ++r) {
      int qr = q0 + w * 16 + quad * 4 + r;
      ctx[(long)(b * S + qr) * CD + h * 64 + nj * 16 + fm] = f2bf(acc_o[nj][r] * li4[r]);
    }
}

// ---------------------------------------------------------------------------
// Final-projection GEMM (N=80), f32 transposed store to d_out.
// ---------------------------------------------------------------------------
template<int BM, int BN>
__global__ __launch_bounds__(256)
void gemmF_k(const u16* __restrict__ A, const u16* __restrict__ Bm,
             float* __restrict__ Cm, const float* __restrict__ bias,
             int M, int N, int K, int lda, int ldb,
             const u16* __restrict__ zp)
{
  __shared__ u16 As[BM * 32];
  __shared__ u16 Bs[BN * 32];

  const int t = threadIdx.x;
  const int lane = t & 63;
  const int wave = t >> 6;
  constexpr int WCOLS = BN / 64;
  const int wrow = wave / WCOLS;
  const int wcol = wave % WCOLS;
  const int bn0 = blockIdx.x * BN;
  const int bm0 = blockIdx.y * BM;

  floatx4 acc[4][4];
#pragma unroll
  for (int i = 0; i < 4; ++i)
#pragma unroll
    for (int j = 0; j < 4; ++j) acc[i][j] = (floatx4){0.f, 0.f, 0.f, 0.f};

  const int rsub = lane >> 2;
  const int g8 = (((lane & 3) ^ ((lane >> 3) & 3)) << 3);
  constexpr int PA = BM / 64, PB = BN / 64;

  const int q = lane >> 4, fm = lane & 15;
  const int swz8 = ((q ^ ((fm >> 1) & 3)) << 3);

  const u16* aP[PA]; const u16* bP[PB];
#pragma unroll
  for (int p = 0; p < PA; ++p)
    aP[p] = A + (long)(bm0 + p * 64 + wave * 16 + rsub) * lda + g8;
#pragma unroll
  for (int p = 0; p < PB; ++p) {
    int r = p * 64 + wave * 16 + rsub;
    bP[p] = ((bn0 + r) < N) ? (Bm + (long)(bn0 + r) * ldb + g8) : nullptr;
  }

  for (int k0 = 0; k0 < K; k0 += 32) {
#pragma unroll
    for (int p = 0; p < PA; ++p)
      gld16(aP[p] + k0, &As[(p * 64 + wave * 16) * 32]);
#pragma unroll
    for (int p = 0; p < PB; ++p)
      gld16(bP[p] ? bP[p] + k0 : zp, &Bs[(p * 64 + wave * 16) * 32]);
    __syncthreads();

    short8 af[4], bfr[4];
#pragma unroll
    for (int i = 0; i < 4; ++i)
      af[i] = *(const short8*)&As[(wrow * 64 + i * 16 + fm) * 32 + swz8];
#pragma unroll
    for (int j = 0; j < 4; ++j)
      bfr[j] = *(const short8*)&Bs[(wcol * 64 + j * 16 + fm) * 32 + swz8];
#pragma unroll
    for (int i = 0; i < 4; ++i)
#pragma unroll
      for (int j = 0; j < 4; ++j)
        acc[i][j] = __builtin_amdgcn_mfma_f32_16x16x32_bf16(af[i], bfr[j], acc[i][j], 0, 0, 0);
    __syncthreads();
  }

  const int rbase = bm0 + wrow * 64 + ((lane >> 4) << 2);
  const int cbase = bn0 + wcol * 64 + (lane & 15);
#pragma unroll
  for (int j = 0; j < 4; ++j) {
    int col = cbase + j * 16;
    if (col >= N) continue;
    float bv = bias ? bias[col] : 0.f;
#pragma unroll
    for (int i = 0; i < 4; ++i) {
#pragma unroll
      for (int r = 0; r < 4; ++r) {
        int row = rbase + i * 16 + r;
        Cm[((long)(row >> 10) * COUT + col) * CMEL + (row & 1023)] = acc[i][j][r] + bv;
      }
    }
  }
}

// ---------------------------------------------------------------------------
// W [tap][K][N] f32 -> WT [tap][N][K] bf16 (LDS-tiled 32x32 transpose)
__global__ void cvt_t_k(const float* __restrict__ src, u16* __restrict__ dst, int K, int N)
{
  const int tap = blockIdx.z;
  const int n0 = blockIdx.x * 32, k0 = blockIdx.y * 32;
  __shared__ float tile[32][33];
  const int t = threadIdx.x;
  const int c = t & 31, rr = t >> 5;
  const float* s = src + (long)tap * K * N;
  u16* d = dst + (long)tap * K * N;
#pragma unroll
  for (int i = 0; i < 4; ++i) {
    int k = k0 + rr + i * 8, n = n0 + c;
    tile[rr + i * 8][c] = (k < K && n < N) ? s[(long)k * N + n] : 0.f;
  }
  __syncthreads();
#pragma unroll
  for (int i = 0; i < 4; ++i) {
    int n = n0 + rr + i * 8, k = k0 + c;
    if (n < N && k < K) d[(long)n * K + k] = f2bf(tile[c][rr + i * 8]);
  }
}

// vt[(b*CH+h)*64 + d][S] = qkv[(b*S+s)*CQKV + 2*CD + h*64 + d]
__global__ void vtr_k(const u16* __restrict__ qkv, u16* __restrict__ vt, int S)
{
  const int s0 = blockIdx.x * 64;
  const int bh = blockIdx.y;
  const int b = bh >> 3, h = bh & 7;
  __shared__ u16 tile[64][65];
  const int t = threadIdx.x;
  const int wave = t >> 6, lane = t & 63;
#pragma unroll
  for (int i = 0; i < 16; ++i) {
    int sl = wave * 16 + i;
    tile[sl][lane] = qkv[(long)(b * S + s0 + sl) * CQKV + 2 * CD + h * 64 + lane];
  }
  __syncthreads();
  const int dl = t >> 2, sc4 = (t & 3) << 4;
  u16* dstp = vt + ((long)bh * 64 + dl) * S + s0 + sc4;
  short8 v0, v1;
#pragma unroll
  for (int j = 0; j < 8; ++j) { v0[j] = (short)tile[sc4 + j][dl]; v1[j] = (short)tile[sc4 + 8 + j][dl]; }
  *(short8*)dstp = v0;
  *(short8*)(dstp + 8) = v1;
}

__global__ void fill_k(float* __restrict__ o, int n, float v)
{
  int i = blockIdx.x * 256 + threadIdx.x;
  if (i < n) o[i] = v;
}

// x[b,t,:] = bf16( 2*emb[tok] + pos[b] )   (reference quirk: pos indexed by BATCH b)
__global__ void embed_k(const int* __restrict__ tok, const float* __restrict__ emb,
                        u16* __restrict__ X)
{
  const long idx = (long)blockIdx.x * 256 + threadIdx.x;
  const int d = (int)(idx & (CD - 1));
  const int m = (int)(idx >> 9);
  const int b = m >> 8;
  const float e = emb[(long)tok[m] * CD + d];
  const int i2 = d >> 1;
  const float den = __expf(-(float)(2 * i2) * (9.210340371976184f / 512.f));
  const float ang = (float)b * den;
  const float p = (d & 1) ? __cosf(ang) : __sinf(ang);
  X[idx] = f2bf(2.f * e + p);
}

// ===========================================================================
// ln_res_k: O = LN(X + Y) * g + b.  Wave-per-row, barrier-free (R12 win).
// ===========================================================================
__global__ __launch_bounds__(256)
void ln_res_k(const u16* __restrict__ X, const u16* __restrict__ Y,
              const float* __restrict__ g, const float* __restrict__ bta,
              u16* __restrict__ O)
{
  const int w = threadIdx.x >> 6, lane = threadIdx.x & 63;
  const long m = (long)blockIdx.x * 4 + w;
  const long base = m * CD + lane * 8;
  const short8 xv = *(const short8*)&X[base];
  const short8 yv = *(const short8*)&Y[base];
  float v[8]; float s = 0.f;
#pragma unroll
  for (int j = 0; j < 8; ++j) { v[j] = bf2f((u16)xv[j]) + bf2f((u16)yv[j]); s += v[j]; }
#pragma unroll
  for (int o = 1; o < 64; o <<= 1) s += __shfl_xor(s, o);
  const float mean = s * (1.f / 512.f);
  float qs = 0.f;
#pragma unroll
  for (int j = 0; j < 8; ++j) { v[j] -= mean; qs += v[j] * v[j]; }
#pragma unroll
  for (int o = 1; o < 64; o <<= 1) qs += __shfl_xor(qs, o);
  const float rstd = rsqrtf(qs * (1.f / 512.f) + 1e-5f);
  const float4 g0 = *(const float4*)&g[lane * 8];
  const float4 g1 = *(const float4*)&g[lane * 8 + 4];
  const float4 b0 = *(const float4*)&bta[lane * 8];
  const float4 b1 = *(const float4*)&bta[lane * 8 + 4];
  short8 ov;
  ov[0] = (short)f2bf(v[0] * rstd * g0.x + b0.x);
  ov[1] = (short)f2bf(v[1] * rstd * g0.y + b0.y);
  ov[2] = (short)f2bf(v[2] * rstd * g0.z + b0.z);
  ov[3] = (short)f2bf(v[3] * rstd * g0.w + b0.w);
  ov[4] = (short)f2bf(v[4] * rstd * g1.x + b1.x);
  ov[5] = (short)f2bf(v[5] * rstd * g1.y + b1.y);
  ov[6] = (short)f2bf(v[6] * rstd * g1.z + b1.z);
  ov[7] = (short)f2bf(v[7] * rstd * g1.w + b1.w);
  *(short8*)&O[base] = ov;
}

__global__ void cumsum_k(const int* __restrict__ dur, int* __restrict__ cums)
{
  int b = threadIdx.x;
  if (b < CB) {
    int s = 0;
    for (int t = 0; t < CT; ++t) { s += dur[b * CT + t]; cums[b * CT + t] = s; }
  }
}

// ===========================================================================
// regulate_k: wave-per-row, short8 vectorized copy (R12 win).
// ===========================================================================
__global__ __launch_bounds__(256)
void regulate_k(const u16* __restrict__ xe, const int* __restrict__ cums,
                const int* __restrict__ mlen, u16* __restrict__ xd)
{
  const int w = threadIdx.x >> 6, lane = threadIdx.x & 63;
  const int m = blockIdx.x * 4 + w;
  const int b = m >> 10, f = m & (CMEL - 1);
  int lo = 0, hi = CT;
  while (lo < hi) { int mid = (lo + hi) >> 1; if (cums[b * CT + mid] <= f) lo = mid + 1; else hi = mid; }
  const int idx = min(lo, CT - 1);
  const bool keep = (f <= mlen[b]);
  short8 val = {};
  if (keep) val = *(const short8*)&xe[((long)b * CT + idx) * CD + lane * 8];
  *(short8*)&xd[(long)m * CD + lane * 8] = val;
}

// ---------------------------------------------------------------------------
extern "C" void kernel_launch(void* const* d_in, const int* in_sizes, int n_in,
                              void* d_out, int out_size, void* d_ws, size_t ws_size,
                              hipStream_t stream)
{
  (void)in_sizes; (void)n_in;
  const int*   tokens = (const int*)d_in[0];
  const int*   tlen   = (const int*)d_in[1];
  const int*   mlen   = (const int*)d_in[2];
  const int*   dur    = (const int*)d_in[3];
  const float* emb    = (const float*)d_in[5];
  const float* ew[12]; const float* dw[12];
  for (int i = 0; i < 12; ++i) { ew[i] = (const float*)d_in[6 + i]; dw[i] = (const float*)d_in[18 + i]; }
  const float* out_w = (const float*)d_in[30];
  const float* out_b = (const float*)d_in[31];

  const int Me = CB * CT;       // 4096
  const int Md = CB * CMEL;     // 16384

  const size_t SZ_ZP   = 256;
  const size_t SZ_WBUF = (size_t)3 * CD * CINTER * 2;
  const size_t SZ_XE   = (size_t)Me * CD * 2;
  const size_t SZ_XD   = (size_t)Md * CD * 2;     // x, x1(ctx), yb(vt)
  const size_t SZ_QKV  = (size_t)Md * CQKV * 2;   // 50.3 MB
  const size_t SZ_HB   = (size_t)Md * CINTER * 2; // 67.1 MB
  const size_t SZ_CUMS = (size_t)CB * CT * 4;
  auto al = [](size_t b) { return (b + 255) & ~(size_t)255; };
  size_t U = al(SZ_QKV) > al(SZ_HB) ? al(SZ_QKV) : al(SZ_HB);
  size_t total = al(SZ_ZP) + al(SZ_WBUF) + al(SZ_XE) + 3 * al(SZ_XD) + U + al(SZ_CUMS);
  if (total > ws_size) {
    fill_k<<<dim3((unsigned)((out_size + 255) / 256)), dim3(256), 0, stream>>>(
        (float*)d_out, out_size, 1000.0f);
    return;
  }

  char* p = (char*)d_ws;
  auto take = [&](size_t bytes) { char* r = p; p += al(bytes); return r; };
  u16*  zp   = (u16*)take(SZ_ZP);
  u16*  wbuf = (u16*)take(SZ_WBUF);
  u16*  xe   = (u16*)take(SZ_XE);
  u16*  xd   = (u16*)take(SZ_XD);
  u16*  x1   = (u16*)take(SZ_XD);   // also ctx during attention
  u16*  yb   = (u16*)take(SZ_XD);   // also vt during attention
  char* U0   = take(U);
  u16*  qkvB = (u16*)U0;
  u16*  hb   = (u16*)U0;
  int* cums = (int*)take(SZ_CUMS);

  hipMemsetAsync(zp, 0, SZ_ZP, stream);

  auto cvtT = [&](const float* s, u16* d, int K, int N, int taps) {
    cvt_t_k<<<dim3((unsigned)((N + 31) / 32), (unsigned)((K + 31) / 32), (unsigned)taps),
              dim3(256), 0, stream>>>(s, d, K, N);
  };

  embed_k<<<dim3((unsigned)((long)Me * CD / 256)), dim3(256), 0, stream>>>(tokens, emb, xe);

  auto run_stack = [&](u16* x, int S, int M, const int* lens, const float* const* W) {
    u16* vt = yb;
    const bool small = (M < 8192);   // encoder: BM=64 for the 128-block GEMMs
    for (int l = 0; l < CL; ++l) {
      // qkv = x @ Wqkv + b
      cvtT(W[0] + (long)l * CD * CQKV, wbuf, CD, CQKV, 1);
      gemm2_k<128, 1, false><<<dim3(CQKV / 128, M / 128), dim3(256), 0, stream>>>(
          x, wbuf, qkvB, W[1] + l * CQKV, M, CQKV, CD, CD, CD, CQKV, S - 1, 0, zp);
      // V^T
      vtr_k<<<dim3((unsigned)(S / 64), (unsigned)(CB * CH)), dim3(256), 0, stream>>>(qkvB, vt, S);
      // fused attention -> ctx (= x1)
      attn_k<<<dim3((unsigned)(S / 128), (unsigned)(CB * CH)), dim3(512), 0, stream>>>(
          qkvB, vt, x1, lens, S);
      // proj: ctx @ Wo + bo -> yb   (encoder: 128 blocks -> BM=64 doubles grid)
      cvtT(W[2] + (long)l * CD * CD, wbuf, CD, CD, 1);
      if (small)
        gemm2_k<64, 1, false><<<dim3(CD / 128, M / 64), dim3(256), 0, stream>>>(
            x1, wbuf, yb, W[3] + l * CD, M, CD, CD, CD, CD, CD, S - 1, 0, zp);
      else
        gemm2_k<128, 1, false><<<dim3(CD / 128, M / 128), dim3(256), 0, stream>>>(
            x1, wbuf, yb, W[3] + l * CD, M, CD, CD, CD, CD, CD, S - 1, 0, zp);
      ln_res_k<<<dim3((unsigned)(M / 4)), dim3(256), 0, stream>>>(
          x, yb, W[4] + l * CD, W[5] + l * CD, x1);
      // conv1 (3-tap) + relu
      cvtT(W[6] + (long)l * 3 * CD * CINTER, wbuf, CD, CINTER, 3);
      gemm2_k<128, 3, true><<<dim3(CINTER / 128, M / 128), dim3(256), 0, stream>>>(
          x1, wbuf, hb, W[7] + l * CINTER, M, CINTER, CD, CD, CD, CINTER,
          S - 1, (long)CD * CINTER, zp);
      // conv2 (3-tap)   (encoder: 128 blocks -> BM=64 doubles grid)
      cvtT(W[8] + (long)l * 3 * CINTER * CD, wbuf, CINTER, CD, 3);
      if (small)
        gemm2_k<64, 3, false><<<dim3(CD / 128, M / 64), dim3(256), 0, stream>>>(
            hb, wbuf, yb, W[9] + l * CD, M, CD, CINTER, CINTER, CINTER, CD,
            S - 1, (long)CINTER * CD, zp);
      else
        gemm2_k<128, 3, false><<<dim3(CD / 128, M / 128), dim3(256), 0, stream>>>(
            hb, wbuf, yb, W[9] + l * CD, M, CD, CINTER, CINTER, CINTER, CD,
            S - 1, (long)CINTER * CD, zp);
      ln_res_k<<<dim3((unsigned)(M / 4)), dim3(256), 0, stream>>>(
          x1, yb, W[10] + l * CD, W[11] + l * CD, x);
    }
  };

  run_stack(xe, CT, Me, tlen, ew);

  cumsum_k<<<dim3(1), dim3(64), 0, stream>>>(dur, cums);
  regulate_k<<<dim3((unsigned)(CB * CMEL / 4)), dim3(256), 0, stream>>>(xe, cums, mlen, xd);

  run_stack(xd, CMEL, Md, mlen, dw);

  // final projection, transposed f32 store straight to d_out
  cvtT(out_w, wbuf, CD, COUT, 1);
  gemmF_k<128, 128><<<dim3(1, Md / 128), dim3(256), 0, stream>>>(
      xd, wbuf, (float*)d_out, out_b, Md, COUT, CD, CD, CD, zp);
}